// Round 1
// baseline (1858.168 us; speedup 1.0000x reference)
//
#include <hip/hip_runtime.h>
#include <math.h>

// Problem constants
#define BB 4
#define TT 2048
#define NTOK 8192        // B*T
#define DIMD 512
#define HH 8
#define DHH 64
#define MLPD 2048
#define ADIMD 256
#define MODD 3072        // 6*DIM
#define LNEPS 1e-5f

// ---------------------------------------------------------------------------
// Templated NT GEMM: C[m,n] = epi( sum_k aop(A[m,k]) * B[n,k] )
// A: MxK row-major (K contiguous), B: NxK row-major (K contiguous).
// BM=BN=64, BK=16, 256 threads, 4x4 micro-tile per thread.
// AOP: 0 = identity, 1 = silu
// EPI: 0 = store acc
//      1 = store acc + bias[n]
//      2 = store gelu_exact(acc + bias[n])
//      3 = store res[m,n] + mod[m*3072+1024+n] * (acc + bias[n])    (gate1 residual)
//      4 = store C[m,n]   + mod[m*3072+2560+n] * (acc + bias[n])    (gate2 residual RMW)
// ---------------------------------------------------------------------------
template<int AOP, int EPI>
__global__ __launch_bounds__(256) void gemm_nt(
    const float* __restrict__ A, const float* __restrict__ Bw,
    const float* __restrict__ bias, const float* __restrict__ res,
    const float* __restrict__ mod,
    int M, int N, int K,
    float* __restrict__ C)
{
    __shared__ float As[16][68];   // [k][m], +4 pad kills bank conflicts
    __shared__ float Bs[16][68];   // [k][n]

    const int tid = threadIdx.x;
    const int tx = tid & 15;       // n direction
    const int ty = tid >> 4;       // m direction
    const int row0 = blockIdx.y * 64;
    const int col0 = blockIdx.x * 64;

    // loader indices: each thread loads one float4 of A and one of B per K-step
    const int lm = tid >> 2;            // 0..63 row within tile
    const int lk = (tid & 3) << 2;      // 0,4,8,12

    float acc[4][4];
    #pragma unroll
    for (int i = 0; i < 4; i++)
        #pragma unroll
        for (int j = 0; j < 4; j++) acc[i][j] = 0.f;

    for (int k0 = 0; k0 < K; k0 += 16) {
        float4 av = *(const float4*)&A[(size_t)(row0 + lm) * K + k0 + lk];
        float4 bv = *(const float4*)&Bw[(size_t)(col0 + lm) * K + k0 + lk];
        if (AOP == 1) {  // silu(x) = x * sigmoid(x)
            av.x = av.x / (1.f + __expf(-av.x));
            av.y = av.y / (1.f + __expf(-av.y));
            av.z = av.z / (1.f + __expf(-av.z));
            av.w = av.w / (1.f + __expf(-av.w));
        }
        __syncthreads();   // previous iteration's compute done before overwrite
        As[lk + 0][lm] = av.x; As[lk + 1][lm] = av.y;
        As[lk + 2][lm] = av.z; As[lk + 3][lm] = av.w;
        Bs[lk + 0][lm] = bv.x; Bs[lk + 1][lm] = bv.y;
        Bs[lk + 2][lm] = bv.z; Bs[lk + 3][lm] = bv.w;
        __syncthreads();

        #pragma unroll
        for (int k = 0; k < 16; k++) {
            float4 a4 = *(const float4*)&As[k][ty << 2];
            float4 b4 = *(const float4*)&Bs[k][tx << 2];
            float ar[4] = {a4.x, a4.y, a4.z, a4.w};
            float br[4] = {b4.x, b4.y, b4.z, b4.w};
            #pragma unroll
            for (int i = 0; i < 4; i++)
                #pragma unroll
                for (int j = 0; j < 4; j++)
                    acc[i][j] += ar[i] * br[j];
        }
    }

    const int gm = row0 + (ty << 2);
    const int gn = col0 + (tx << 2);
    #pragma unroll
    for (int i = 0; i < 4; i++) {
        const int row = gm + i;
        #pragma unroll
        for (int j = 0; j < 4; j++) {
            const int col = gn + j;
            const size_t idx = (size_t)row * N + col;
            float v = acc[i][j];
            if (EPI == 0) {
                C[idx] = v;
            } else if (EPI == 1) {
                C[idx] = v + bias[col];
            } else if (EPI == 2) {
                float t = v + bias[col];
                C[idx] = 0.5f * t * (1.f + erff(t * 0.70710678118654752f));
            } else if (EPI == 3) {
                float t = v + bias[col];
                C[idx] = res[idx] + mod[(size_t)row * MODD + 1024 + col] * t;
            } else if (EPI == 4) {
                float t = v + bias[col];
                C[idx] = C[idx] + mod[(size_t)row * MODD + 2560 + col] * t;
            }
        }
    }
}

// ---------------------------------------------------------------------------
// adaLN: dst[n,:] = LN(src[n,:]) * (1 + mod[n, scale_off:+512]) + mod[n, shift_off:+512]
// One block per token, 256 threads, 2 elements each.
// ---------------------------------------------------------------------------
__global__ __launch_bounds__(256) void adaln_ln(
    const float* __restrict__ src, const float* __restrict__ mod,
    float* __restrict__ dst, int shift_off, int scale_off)
{
    const int n = blockIdx.x;
    const int tid = threadIdx.x;
    const float* xr = src + (size_t)n * DIMD;
    float v0 = xr[tid], v1 = xr[tid + 256];
    float s = v0 + v1;
    float q = v0 * v0 + v1 * v1;
    #pragma unroll
    for (int o = 32; o > 0; o >>= 1) {
        s += __shfl_down(s, o);
        q += __shfl_down(q, o);
    }
    __shared__ float sh[8];
    __shared__ float mu_sh, rs_sh;
    const int wid = tid >> 6, lane = tid & 63;
    if (lane == 0) { sh[wid] = s; sh[wid + 4] = q; }
    __syncthreads();
    if (tid == 0) {
        float S = sh[0] + sh[1] + sh[2] + sh[3];
        float Q = sh[4] + sh[5] + sh[6] + sh[7];
        float mu = S * (1.f / DIMD);
        float var = Q * (1.f / DIMD) - mu * mu;
        mu_sh = mu;
        rs_sh = rsqrtf(var + LNEPS);
    }
    __syncthreads();
    const float mu = mu_sh, rs = rs_sh;
    const float* mrow = mod + (size_t)n * MODD;
    const size_t o0 = (size_t)n * DIMD + tid;
    dst[o0]       = (v0 - mu) * rs * (1.f + mrow[scale_off + tid])       + mrow[shift_off + tid];
    dst[o0 + 256] = (v1 - mu) * rs * (1.f + mrow[scale_off + tid + 256]) + mrow[shift_off + tid + 256];
}

// ---------------------------------------------------------------------------
// Flash attention (fp32, causal). qkv: [NTOK, 3*512] with q/k/v at +0/+512/+1024,
// inner layout h*64+d. out: [NTOK, 512].
// Grid: (T/32, H, B). Block: 256 threads. Each block: 32 q-rows of one (b,h).
// Thread t: score row r = t/8, score cols (t%8)*4..+3, output cols (t%8)*8..+7.
// ---------------------------------------------------------------------------
__global__ __launch_bounds__(256) void attn_flash(
    const float* __restrict__ qkv, float* __restrict__ out)
{
    __shared__ float Qs[32][68];
    __shared__ float Ks[32][68];
    __shared__ float Vs[32][64];
    __shared__ float Ps[32][36];

    const int qi = blockIdx.x;   // q tile 0..63
    const int h  = blockIdx.y;
    const int b  = blockIdx.z;
    const int tid = threadIdx.x;

    const int r  = tid >> 3;          // 0..31
    const int c4 = (tid & 7) << 2;    // 0..28
    const int vc = (tid & 7) << 3;    // 0..56
    const int qrow0 = qi * 32;

    // load Q tile
    for (int i = tid; i < 512; i += 256) {
        const int rr = i >> 4;
        const int cc = (i & 15) << 2;
        *(float4*)&Qs[rr][cc] =
            *(const float4*)&qkv[((size_t)(b * TT + qrow0 + rr)) * 1536 + h * 64 + cc];
    }

    float m = -INFINITY, l = 0.f;
    float O[8];
    #pragma unroll
    for (int j = 0; j < 8; j++) O[j] = 0.f;
    __syncthreads();

    for (int kt = 0; kt <= qi; ++kt) {
        // load K/V tile
        for (int i = tid; i < 512; i += 256) {
            const int rr = i >> 4;
            const int cc = (i & 15) << 2;
            const size_t base = ((size_t)(b * TT + kt * 32 + rr)) * 1536 + h * 64 + cc;
            *(float4*)&Ks[rr][cc] = *(const float4*)&qkv[base + 512];
            *(float4*)&Vs[rr][cc] = *(const float4*)&qkv[base + 1024];
        }
        __syncthreads();

        // scores: 4 dots of length 64
        float s[4] = {0.f, 0.f, 0.f, 0.f};
        #pragma unroll
        for (int k = 0; k < 64; k += 4) {
            float4 qv = *(const float4*)&Qs[r][k];
            #pragma unroll
            for (int j = 0; j < 4; j++) {
                float4 kv = *(const float4*)&Ks[c4 + j][k];
                s[j] += qv.x * kv.x + qv.y * kv.y + qv.z * kv.z + qv.w * kv.w;
            }
        }
        const int qglob = qrow0 + r;
        float tmax = -INFINITY;
        #pragma unroll
        for (int j = 0; j < 4; j++) {
            const int kglob = kt * 32 + c4 + j;
            s[j] = (kglob <= qglob) ? s[j] * 0.125f : -INFINITY;
            tmax = fmaxf(tmax, s[j]);
        }
        #pragma unroll
        for (int o = 4; o > 0; o >>= 1) tmax = fmaxf(tmax, __shfl_xor(tmax, o, 8));
        const float mnew = fmaxf(m, tmax);
        const float alpha = __expf(m - mnew);    // m=-inf first time -> 0
        float p[4], tsum = 0.f;
        #pragma unroll
        for (int j = 0; j < 4; j++) { p[j] = __expf(s[j] - mnew); tsum += p[j]; }
        #pragma unroll
        for (int o = 4; o > 0; o >>= 1) tsum += __shfl_xor(tsum, o, 8);
        l = l * alpha + tsum;
        m = mnew;
        #pragma unroll
        for (int j = 0; j < 8; j++) O[j] *= alpha;
        *(float4*)&Ps[r][c4] = make_float4(p[0], p[1], p[2], p[3]);
        __syncthreads();

        // O += P @ V
        #pragma unroll 4
        for (int k = 0; k < 32; k++) {
            const float pv = Ps[r][k];
            float4 v0 = *(const float4*)&Vs[k][vc];
            float4 v1 = *(const float4*)&Vs[k][vc + 4];
            O[0] += pv * v0.x; O[1] += pv * v0.y; O[2] += pv * v0.z; O[3] += pv * v0.w;
            O[4] += pv * v1.x; O[5] += pv * v1.y; O[6] += pv * v1.z; O[7] += pv * v1.w;
        }
        __syncthreads();   // before next tile overwrites Ks/Vs/Ps
    }

    const float inv = 1.f / l;
    const size_t orow = (size_t)(b * TT + qrow0 + r) * DIMD + h * 64 + vc;
    *(float4*)&out[orow]     = make_float4(O[0] * inv, O[1] * inv, O[2] * inv, O[3] * inv);
    *(float4*)&out[orow + 4] = make_float4(O[4] * inv, O[5] * inv, O[6] * inv, O[7] * inv);
}

// ---------------------------------------------------------------------------
extern "C" void kernel_launch(void* const* d_in, const int* in_sizes, int n_in,
                              void* d_out, int out_size, void* d_ws, size_t ws_size,
                              hipStream_t stream)
{
    (void)in_sizes; (void)n_in; (void)out_size; (void)ws_size;

    const float* x    = (const float*)d_in[0];   // (4,2048,512)
    const float* aemb = (const float*)d_in[1];   // (4,2048,256)
    // d_in[2] = causal_mask (unused; causality computed analytically)
    const float* Wqkv = (const float*)d_in[3];   // (1536,512)
    const float* Wout = (const float*)d_in[4];   // (512,512)
    const float* bout = (const float*)d_in[5];   // (512)
    const float* W1   = (const float*)d_in[6];   // (2048,512)
    const float* b1   = (const float*)d_in[7];   // (2048)
    const float* W2   = (const float*)d_in[8];   // (512,2048)
    const float* b2   = (const float*)d_in[9];   // (512)
    const float* Wmod = (const float*)d_in[10];  // (3072,256)
    const float* bmod = (const float*)d_in[11];  // (3072)

    float* out = (float*)d_out;                  // (4,2048,512); also holds x_mid
    float* ws  = (float*)d_ws;

    // workspace layout (floats):
    float* modw = ws;                                  // 8192*3072 = 25165824
    float* h1   = modw + (size_t)NTOK * MODD;          // 8192*512
    float* qkvw = h1   + (size_t)NTOK * DIMD;          // 8192*1536
    float* attw = qkvw + (size_t)NTOK * 1536;          // 8192*512
    float* h2   = h1;                                  // reuse (h1 dead after QKV)
    float* hid  = qkvw;                                // 8192*2048, reuses qkv+attn

    // 1) mod = silu(action_emb) @ Wmod^T + bmod
    gemm_nt<1, 1><<<dim3(MODD / 64, NTOK / 64), 256, 0, stream>>>(
        aemb, Wmod, bmod, nullptr, nullptr, NTOK, MODD, ADIMD, modw);

    // 2) h1 = LN(x)*(1+scale1)+shift1
    adaln_ln<<<NTOK, 256, 0, stream>>>(x, modw, h1, 0, 512);

    // 3) qkv = h1 @ Wqkv^T
    gemm_nt<0, 0><<<dim3(1536 / 64, NTOK / 64), 256, 0, stream>>>(
        h1, Wqkv, nullptr, nullptr, nullptr, NTOK, 1536, DIMD, qkvw);

    // 4) attention
    attn_flash<<<dim3(TT / 32, HH, BB), 256, 0, stream>>>(qkvw, attw);

    // 5) x_mid = x + gate1 * (attw @ Wout^T + bout)   -> d_out
    gemm_nt<0, 3><<<dim3(DIMD / 64, NTOK / 64), 256, 0, stream>>>(
        attw, Wout, bout, x, modw, NTOK, DIMD, DIMD, out);

    // 6) h2 = LN(x_mid)*(1+scale2)+shift2
    adaln_ln<<<NTOK, 256, 0, stream>>>(out, modw, h2, 1536, 2048);

    // 7) hid = gelu(h2 @ W1^T + b1)
    gemm_nt<0, 2><<<dim3(MLPD / 64, NTOK / 64), 256, 0, stream>>>(
        h2, W1, b1, nullptr, nullptr, NTOK, MLPD, DIMD, hid);

    // 8) d_out = x_mid + gate2 * (hid @ W2^T + b2)
    gemm_nt<0, 4><<<dim3(DIMD / 64, NTOK / 64), 256, 0, stream>>>(
        hid, W2, b2, nullptr, modw, NTOK, DIMD, MLPD, out);
}

// Round 2
// 1194.665 us; speedup vs baseline: 1.5554x; 1.5554x over previous
//
#include <hip/hip_runtime.h>
#include <math.h>

// Problem constants
#define BB 4
#define TT 2048
#define NTOK 8192        // B*T
#define DIMD 512
#define HH 8
#define DHH 64
#define MLPD 2048
#define ADIMD 256
#define MODD 3072        // 6*DIM
#define LNEPS 1e-5f

typedef short short8 __attribute__((ext_vector_type(8)));
typedef __bf16 bf16x8 __attribute__((ext_vector_type(8)));
typedef float f32x4 __attribute__((ext_vector_type(4)));

static __device__ __forceinline__ unsigned short f2bf(float f) {
    union { float f; unsigned u; } v; v.f = f;
    unsigned r = v.u + 0x7fffu + ((v.u >> 16) & 1u);
    return (unsigned short)(r >> 16);
}

static __device__ __forceinline__ f32x4 mfma_bf16(short8 a, short8 b, f32x4 c) {
    return __builtin_amdgcn_mfma_f32_16x16x32_bf16(
        __builtin_bit_cast(bf16x8, a), __builtin_bit_cast(bf16x8, b), c, 0, 0, 0);
}

// ---------------------------------------------------------------------------
// Templated NT GEMM (fp32): C[m,n] = epi( sum_k aop(A[m,k]) * B[n,k] )
// ---------------------------------------------------------------------------
template<int AOP, int EPI>
__global__ __launch_bounds__(256) void gemm_nt(
    const float* __restrict__ A, const float* __restrict__ Bw,
    const float* __restrict__ bias, const float* __restrict__ res,
    const float* __restrict__ mod,
    int M, int N, int K,
    float* __restrict__ C)
{
    __shared__ float As[16][68];
    __shared__ float Bs[16][68];

    const int tid = threadIdx.x;
    const int tx = tid & 15;
    const int ty = tid >> 4;
    const int row0 = blockIdx.y * 64;
    const int col0 = blockIdx.x * 64;

    const int lm = tid >> 2;
    const int lk = (tid & 3) << 2;

    float acc[4][4];
    #pragma unroll
    for (int i = 0; i < 4; i++)
        #pragma unroll
        for (int j = 0; j < 4; j++) acc[i][j] = 0.f;

    for (int k0 = 0; k0 < K; k0 += 16) {
        float4 av = *(const float4*)&A[(size_t)(row0 + lm) * K + k0 + lk];
        float4 bv = *(const float4*)&Bw[(size_t)(col0 + lm) * K + k0 + lk];
        if (AOP == 1) {
            av.x = av.x / (1.f + __expf(-av.x));
            av.y = av.y / (1.f + __expf(-av.y));
            av.z = av.z / (1.f + __expf(-av.z));
            av.w = av.w / (1.f + __expf(-av.w));
        }
        __syncthreads();
        As[lk + 0][lm] = av.x; As[lk + 1][lm] = av.y;
        As[lk + 2][lm] = av.z; As[lk + 3][lm] = av.w;
        Bs[lk + 0][lm] = bv.x; Bs[lk + 1][lm] = bv.y;
        Bs[lk + 2][lm] = bv.z; Bs[lk + 3][lm] = bv.w;
        __syncthreads();

        #pragma unroll
        for (int k = 0; k < 16; k++) {
            float4 a4 = *(const float4*)&As[k][ty << 2];
            float4 b4 = *(const float4*)&Bs[k][tx << 2];
            float ar[4] = {a4.x, a4.y, a4.z, a4.w};
            float br[4] = {b4.x, b4.y, b4.z, b4.w};
            #pragma unroll
            for (int i = 0; i < 4; i++)
                #pragma unroll
                for (int j = 0; j < 4; j++)
                    acc[i][j] += ar[i] * br[j];
        }
    }

    const int gm = row0 + (ty << 2);
    const int gn = col0 + (tx << 2);
    #pragma unroll
    for (int i = 0; i < 4; i++) {
        const int row = gm + i;
        #pragma unroll
        for (int j = 0; j < 4; j++) {
            const int col = gn + j;
            const size_t idx = (size_t)row * N + col;
            float v = acc[i][j];
            if (EPI == 0) {
                C[idx] = v;
            } else if (EPI == 1) {
                C[idx] = v + bias[col];
            } else if (EPI == 2) {
                float t = v + bias[col];
                C[idx] = 0.5f * t * (1.f + erff(t * 0.70710678118654752f));
            } else if (EPI == 3) {
                float t = v + bias[col];
                C[idx] = res[idx] + mod[(size_t)row * MODD + 1024 + col] * t;
            } else if (EPI == 4) {
                float t = v + bias[col];
                C[idx] = C[idx] + mod[(size_t)row * MODD + 2560 + col] * t;
            }
        }
    }
}

// ---------------------------------------------------------------------------
// adaLN
// ---------------------------------------------------------------------------
__global__ __launch_bounds__(256) void adaln_ln(
    const float* __restrict__ src, const float* __restrict__ mod,
    float* __restrict__ dst, int shift_off, int scale_off)
{
    const int n = blockIdx.x;
    const int tid = threadIdx.x;
    const float* xr = src + (size_t)n * DIMD;
    float v0 = xr[tid], v1 = xr[tid + 256];
    float s = v0 + v1;
    float q = v0 * v0 + v1 * v1;
    #pragma unroll
    for (int o = 32; o > 0; o >>= 1) {
        s += __shfl_down(s, o);
        q += __shfl_down(q, o);
    }
    __shared__ float sh[8];
    __shared__ float mu_sh, rs_sh;
    const int wid = tid >> 6, lane = tid & 63;
    if (lane == 0) { sh[wid] = s; sh[wid + 4] = q; }
    __syncthreads();
    if (tid == 0) {
        float S = sh[0] + sh[1] + sh[2] + sh[3];
        float Q = sh[4] + sh[5] + sh[6] + sh[7];
        float mu = S * (1.f / DIMD);
        float var = Q * (1.f / DIMD) - mu * mu;
        mu_sh = mu;
        rs_sh = rsqrtf(var + LNEPS);
    }
    __syncthreads();
    const float mu = mu_sh, rs = rs_sh;
    const float* mrow = mod + (size_t)n * MODD;
    const size_t o0 = (size_t)n * DIMD + tid;
    dst[o0]       = (v0 - mu) * rs * (1.f + mrow[scale_off + tid])       + mrow[shift_off + tid];
    dst[o0 + 256] = (v1 - mu) * rs * (1.f + mrow[scale_off + tid + 256]) + mrow[shift_off + tid + 256];
}

// ---------------------------------------------------------------------------
// MFMA flash attention (bf16 compute, fp32 accumulate), causal.
// qkv: [NTOK, 1536] fp32 (q/k/v at +0/+512/+1024, inner h*64+d). out: [NTOK,512].
// Grid: (T/128=16, H, B), block 256 = 4 waves. Block handles 128 q rows;
// wave w handles 32 rows (2 m-tiles of 16). K-tiles of 64 positions.
// Layouts (verified m89/m120):
//   A-frag: A[m=lane&15][k=quad*8+j]   B-frag: B[k=quad*8+j][n=lane&15]
//   C/D:    col=lane&15, row=quad*4+reg
// ---------------------------------------------------------------------------
__global__ __launch_bounds__(256) void attn_mfma(
    const float* __restrict__ qkv, float* __restrict__ out)
{
    __shared__ unsigned short Kt[64][72];     // K[kpos][d], bf16, +8 pad
    __shared__ unsigned short Vt[64][72];     // V^T: Vt[d][kpos]
    __shared__ unsigned short Ps[4][32][72];  // per-wave P[q][kpos]

    const int qi = (TT / 128 - 1) - blockIdx.x;   // reversed: long blocks first
    const int h = blockIdx.y, b = blockIdx.z;
    const int tid = threadIdx.x;
    const int w = tid >> 6;
    const int lane = tid & 63;
    const int quad = lane >> 4;
    const int l16 = lane & 15;

    const int q0 = qi * 128;
    const int qw = q0 + w * 32;
    const size_t tokbase = (size_t)b * TT;

    // Q fragments, 1/8 scale folded into bf16 convert
    short8 qf[2][2];
    #pragma unroll
    for (int mt = 0; mt < 2; mt++) {
        const float* qp = qkv + (tokbase + qw + mt * 16 + l16) * 1536 + h * 64 + quad * 8;
        #pragma unroll
        for (int hh = 0; hh < 2; hh++) {
            float4 a = *(const float4*)(qp + hh * 32);
            float4 c = *(const float4*)(qp + hh * 32 + 4);
            short8 f;
            f[0] = (short)f2bf(a.x * 0.125f); f[1] = (short)f2bf(a.y * 0.125f);
            f[2] = (short)f2bf(a.z * 0.125f); f[3] = (short)f2bf(a.w * 0.125f);
            f[4] = (short)f2bf(c.x * 0.125f); f[5] = (short)f2bf(c.y * 0.125f);
            f[6] = (short)f2bf(c.z * 0.125f); f[7] = (short)f2bf(c.w * 0.125f);
            qf[mt][hh] = f;
        }
    }

    f32x4 Oa[2][4];
    float mrow[2][4], lrow[2][4];
    #pragma unroll
    for (int mt = 0; mt < 2; mt++) {
        #pragma unroll
        for (int dt = 0; dt < 4; dt++) Oa[mt][dt] = (f32x4){0.f, 0.f, 0.f, 0.f};
        #pragma unroll
        for (int r = 0; r < 4; r++) { mrow[mt][r] = -INFINITY; lrow[mt][r] = 0.f; }
    }

    const int nkt = qi * 2 + 2;
    for (int kt = 0; kt < nkt; kt++) {
        // ---- stage K tile: Kt[k][d] (bf16, packed u64 writes) ----
        #pragma unroll
        for (int it = 0; it < 4; it++) {
            const int i = tid + it * 256;
            const int kk = i >> 4, d0 = (i & 15) << 2;
            const float4 k4 = *(const float4*)(qkv + (tokbase + kt * 64 + kk) * 1536 + 512 + h * 64 + d0);
            unsigned long long pk =
                (unsigned long long)f2bf(k4.x)
                | ((unsigned long long)f2bf(k4.y) << 16)
                | ((unsigned long long)f2bf(k4.z) << 32)
                | ((unsigned long long)f2bf(k4.w) << 48);
            *(unsigned long long*)&Kt[kk][d0] = pk;
        }
        // ---- stage V transposed: Vt[d][k] (paired rows -> dword writes) ----
        #pragma unroll
        for (int p = 0; p < 2; p++) {
            const int k0 = (tid & 31) << 1;
            const int d0 = (p << 5) + ((tid >> 5) << 2);
            const float* vp = qkv + (tokbase + kt * 64 + k0) * 1536 + 1024 + h * 64 + d0;
            const float4 va = *(const float4*)vp;
            const float4 vb = *(const float4*)(vp + 1536);
            *(unsigned*)&Vt[d0 + 0][k0] = (unsigned)f2bf(va.x) | ((unsigned)f2bf(vb.x) << 16);
            *(unsigned*)&Vt[d0 + 1][k0] = (unsigned)f2bf(va.y) | ((unsigned)f2bf(vb.y) << 16);
            *(unsigned*)&Vt[d0 + 2][k0] = (unsigned)f2bf(va.z) | ((unsigned)f2bf(vb.z) << 16);
            *(unsigned*)&Vt[d0 + 3][k0] = (unsigned)f2bf(va.w) | ((unsigned)f2bf(vb.w) << 16);
        }
        __syncthreads();

        if (kt * 64 <= qw + 31) {   // wave has live rows in this k-tile
            // ---- S = Q K^T ----
            f32x4 sacc[2][4];
            #pragma unroll
            for (int mt = 0; mt < 2; mt++)
                #pragma unroll
                for (int nt = 0; nt < 4; nt++) sacc[mt][nt] = (f32x4){0.f, 0.f, 0.f, 0.f};
            #pragma unroll
            for (int nt = 0; nt < 4; nt++) {
                const short8 kf0 = *(const short8*)&Kt[nt * 16 + l16][quad * 8];
                const short8 kf1 = *(const short8*)&Kt[nt * 16 + l16][32 + quad * 8];
                #pragma unroll
                for (int mt = 0; mt < 2; mt++) {
                    sacc[mt][nt] = mfma_bf16(qf[mt][0], kf0, sacc[mt][nt]);
                    sacc[mt][nt] = mfma_bf16(qf[mt][1], kf1, sacc[mt][nt]);
                }
            }
            // ---- mask + online softmax + write P ----
            #pragma unroll
            for (int mt = 0; mt < 2; mt++) {
                const int qb = qw + mt * 16;
                if (kt * 64 + 63 > qb) {
                    #pragma unroll
                    for (int nt = 0; nt < 4; nt++) {
                        const int kg = kt * 64 + nt * 16 + l16;
                        #pragma unroll
                        for (int r = 0; r < 4; r++)
                            if (kg > qb + quad * 4 + r) sacc[mt][nt][r] = -INFINITY;
                    }
                }
                #pragma unroll
                for (int r = 0; r < 4; r++) {
                    float tm = fmaxf(fmaxf(sacc[mt][0][r], sacc[mt][1][r]),
                                     fmaxf(sacc[mt][2][r], sacc[mt][3][r]));
                    tm = fmaxf(tm, __shfl_xor(tm, 1));
                    tm = fmaxf(tm, __shfl_xor(tm, 2));
                    tm = fmaxf(tm, __shfl_xor(tm, 4));
                    tm = fmaxf(tm, __shfl_xor(tm, 8));
                    const float mn = fmaxf(mrow[mt][r], tm);
                    const float alpha = __expf(mrow[mt][r] - mn);
                    mrow[mt][r] = mn;
                    float ts = 0.f;
                    float p0 = __expf(sacc[mt][0][r] - mn);
                    float p1 = __expf(sacc[mt][1][r] - mn);
                    float p2 = __expf(sacc[mt][2][r] - mn);
                    float p3 = __expf(sacc[mt][3][r] - mn);
                    ts = p0 + p1 + p2 + p3;
                    ts += __shfl_xor(ts, 1);
                    ts += __shfl_xor(ts, 2);
                    ts += __shfl_xor(ts, 4);
                    ts += __shfl_xor(ts, 8);
                    lrow[mt][r] = lrow[mt][r] * alpha + ts;
                    #pragma unroll
                    for (int dt = 0; dt < 4; dt++) Oa[mt][dt][r] *= alpha;
                    const int prow = mt * 16 + quad * 4 + r;
                    Ps[w][prow][l16]      = f2bf(p0);
                    Ps[w][prow][16 + l16] = f2bf(p1);
                    Ps[w][prow][32 + l16] = f2bf(p2);
                    Ps[w][prow][48 + l16] = f2bf(p3);
                }
            }
            __threadfence_block();  // intra-wave LDS RAW ordering (no barrier: divergent)
            // ---- O += P V ----
            short8 pf[2][2];
            #pragma unroll
            for (int mt = 0; mt < 2; mt++) {
                pf[mt][0] = *(const short8*)&Ps[w][mt * 16 + l16][quad * 8];
                pf[mt][1] = *(const short8*)&Ps[w][mt * 16 + l16][32 + quad * 8];
            }
            #pragma unroll
            for (int dt = 0; dt < 4; dt++) {
                const short8 vf0 = *(const short8*)&Vt[dt * 16 + l16][quad * 8];
                const short8 vf1 = *(const short8*)&Vt[dt * 16 + l16][32 + quad * 8];
                #pragma unroll
                for (int mt = 0; mt < 2; mt++) {
                    Oa[mt][dt] = mfma_bf16(pf[mt][0], vf0, Oa[mt][dt]);
                    Oa[mt][dt] = mfma_bf16(pf[mt][1], vf1, Oa[mt][dt]);
                }
            }
        }
        __syncthreads();
    }

    // ---- epilogue: O /= l ----
    #pragma unroll
    for (int mt = 0; mt < 2; mt++) {
        float inv[4];
        #pragma unroll
        for (int r = 0; r < 4; r++) inv[r] = 1.f / lrow[mt][r];
        #pragma unroll
        for (int dt = 0; dt < 4; dt++) {
            #pragma unroll
            for (int r = 0; r < 4; r++) {
                out[(tokbase + qw + mt * 16 + quad * 4 + r) * DIMD + h * 64 + dt * 16 + l16]
                    = Oa[mt][dt][r] * inv[r];
            }
        }
    }
}

// ---------------------------------------------------------------------------
extern "C" void kernel_launch(void* const* d_in, const int* in_sizes, int n_in,
                              void* d_out, int out_size, void* d_ws, size_t ws_size,
                              hipStream_t stream)
{
    (void)in_sizes; (void)n_in; (void)out_size; (void)ws_size;

    const float* x    = (const float*)d_in[0];
    const float* aemb = (const float*)d_in[1];
    const float* Wqkv = (const float*)d_in[3];
    const float* Wout = (const float*)d_in[4];
    const float* bout = (const float*)d_in[5];
    const float* W1   = (const float*)d_in[6];
    const float* b1   = (const float*)d_in[7];
    const float* W2   = (const float*)d_in[8];
    const float* b2   = (const float*)d_in[9];
    const float* Wmod = (const float*)d_in[10];
    const float* bmod = (const float*)d_in[11];

    float* out = (float*)d_out;
    float* ws  = (float*)d_ws;

    float* modw = ws;                                  // 8192*3072
    float* h1   = modw + (size_t)NTOK * MODD;          // 8192*512
    float* qkvw = h1   + (size_t)NTOK * DIMD;          // 8192*1536
    float* attw = qkvw + (size_t)NTOK * 1536;          // 8192*512
    float* h2   = h1;
    float* hid  = qkvw;                                // 8192*2048 (reuse)

    // 1) mod = silu(action_emb) @ Wmod^T + bmod
    gemm_nt<1, 1><<<dim3(MODD / 64, NTOK / 64), 256, 0, stream>>>(
        aemb, Wmod, bmod, nullptr, nullptr, NTOK, MODD, ADIMD, modw);

    // 2) h1 = LN(x)*(1+scale1)+shift1
    adaln_ln<<<NTOK, 256, 0, stream>>>(x, modw, h1, 0, 512);

    // 3) qkv = h1 @ Wqkv^T
    gemm_nt<0, 0><<<dim3(1536 / 64, NTOK / 64), 256, 0, stream>>>(
        h1, Wqkv, nullptr, nullptr, nullptr, NTOK, 1536, DIMD, qkvw);

    // 4) attention (bf16 MFMA flash)
    attn_mfma<<<dim3(TT / 128, HH, BB), 256, 0, stream>>>(qkvw, attw);

    // 5) x_mid = x + gate1 * (attw @ Wout^T + bout)   -> d_out
    gemm_nt<0, 3><<<dim3(DIMD / 64, NTOK / 64), 256, 0, stream>>>(
        attw, Wout, bout, x, modw, NTOK, DIMD, DIMD, out);

    // 6) h2 = LN(x_mid)*(1+scale2)+shift2
    adaln_ln<<<NTOK, 256, 0, stream>>>(out, modw, h2, 1536, 2048);

    // 7) hid = gelu(h2 @ W1^T + b1)
    gemm_nt<0, 2><<<dim3(MLPD / 64, NTOK / 64), 256, 0, stream>>>(
        h2, W1, b1, nullptr, nullptr, NTOK, MLPD, DIMD, hid);

    // 8) d_out = x_mid + gate2 * (hid @ W2^T + b2)
    gemm_nt<0, 4><<<dim3(DIMD / 64, NTOK / 64), 256, 0, stream>>>(
        hid, W2, b2, nullptr, modw, NTOK, DIMD, MLPD, out);
}

// Round 3
// 432.631 us; speedup vs baseline: 4.2950x; 2.7614x over previous
//
#include <hip/hip_runtime.h>
#include <math.h>
#include <stdint.h>

// Problem constants
#define BB 4
#define TT 2048
#define NTOK 8192        // B*T
#define DIMD 512
#define HH 8
#define DHH 64
#define MLPD 2048
#define ADIMD 256
#define MODD 3072        // 6*DIM
#define LNEPS 1e-5f

typedef short short8 __attribute__((ext_vector_type(8)));
typedef short short4v __attribute__((ext_vector_type(4)));
typedef unsigned short ushort4v __attribute__((ext_vector_type(4)));
typedef __bf16 bf16x8 __attribute__((ext_vector_type(8)));
typedef float f32x4 __attribute__((ext_vector_type(4)));

static __device__ __forceinline__ unsigned short f2bf(float f) {
    union { float f; unsigned u; } v; v.f = f;
    unsigned r = v.u + 0x7fffu + ((v.u >> 16) & 1u);
    return (unsigned short)(r >> 16);
}

static __device__ __forceinline__ f32x4 mfma_bf16(short8 a, short8 b, f32x4 c) {
    return __builtin_amdgcn_mfma_f32_16x16x32_bf16(
        __builtin_bit_cast(bf16x8, a), __builtin_bit_cast(bf16x8, b), c, 0, 0, 0);
}

// async global->LDS, 16B per lane; lds dest must be wave-uniform base (+lane*16)
static __device__ __forceinline__ void gld16(const void* g, const void* l) {
    __builtin_amdgcn_global_load_lds(
        (const __attribute__((address_space(1))) unsigned*)(unsigned long long)(uintptr_t)g,
        (__attribute__((address_space(3))) unsigned*)(unsigned)(uintptr_t)l,
        16, 0, 0);
}

// ---------------------------------------------------------------------------
// fp32 -> bf16 conversion (optionally with silu), 4 elems/thread
// ---------------------------------------------------------------------------
template<int SILU>
__global__ __launch_bounds__(256) void cvt_bf16(
    const float* __restrict__ s, unsigned short* __restrict__ d, int n4)
{
    const int i = blockIdx.x * 256 + threadIdx.x;
    if (i >= n4) return;
    float4 v = ((const float4*)s)[i];
    if (SILU) {
        v.x = v.x / (1.f + __expf(-v.x));
        v.y = v.y / (1.f + __expf(-v.y));
        v.z = v.z / (1.f + __expf(-v.z));
        v.w = v.w / (1.f + __expf(-v.w));
    }
    ushort4v o = { f2bf(v.x), f2bf(v.y), f2bf(v.z), f2bf(v.w) };
    ((ushort4v*)d)[i] = o;
}

// ---------------------------------------------------------------------------
// bf16 MFMA NT GEMM (m97 structure): C[m,n] = epi( sum_k A[m,k]*B[n,k] )
// A: MxK bf16 row-major, B: NxK bf16 row-major. 128x128 tile, BK=32,
// 256 threads = 4 waves, each wave 64x64 (4x4 grid of 16x16x32 MFMA).
// EPI: 0 = bf16 store
//      1 = fp32 store acc + bias[n]
//      2 = bf16 store gelu_exact(acc + bias[n])
//      3 = fp32 store res[m,n] + mod[m*3072+1024+n]*(acc+bias[n])
//      4 = fp32 RMW    C[m,n] + mod[m*3072+2560+n]*(acc+bias[n])
// ---------------------------------------------------------------------------
template<int EPI>
__global__ __launch_bounds__(256) void gemm_bf16(
    const unsigned short* __restrict__ A, const unsigned short* __restrict__ Bw,
    const float* __restrict__ bias, const float* __restrict__ res,
    const float* __restrict__ mod,
    int M, int N, int K,
    void* __restrict__ Cv)
{
    __shared__ unsigned short As[128 * 32];
    __shared__ unsigned short Bs[128 * 32];

    const int tid = threadIdx.x;
    const int w = tid >> 6, lane = tid & 63;
    const int quad = lane >> 4, l16 = lane & 15;
    const int wrow = (w >> 1) * 64, wcol = (w & 1) * 64;
    const int row0 = blockIdx.y * 128, col0 = blockIdx.x * 128;

    const int lrow = lane >> 2;        // 0..15 row within 16-row chunk
    const int lch  = (lane & 3) * 8;   // element offset of 16B chunk

    f32x4 acc[4][4];
    #pragma unroll
    for (int i = 0; i < 4; i++)
        #pragma unroll
        for (int j = 0; j < 4; j++) acc[i][j] = (f32x4){0.f, 0.f, 0.f, 0.f};

    for (int k0 = 0; k0 < K; k0 += 32) {
        __syncthreads();   // previous iter's reads done
        #pragma unroll
        for (int c = 0; c < 2; c++) {
            const int r = w * 16 + c * 64;   // wave-uniform
            gld16(&A[(size_t)(row0 + r + lrow) * K + k0 + lch], &As[r * 32]);
            gld16(&Bw[(size_t)(col0 + r + lrow) * K + k0 + lch], &Bs[r * 32]);
        }
        __syncthreads();   // staging visible

        short8 af[4], bf[4];
        #pragma unroll
        for (int mt = 0; mt < 4; mt++)
            af[mt] = *(const short8*)&As[(wrow + mt * 16 + l16) * 32 + quad * 8];
        #pragma unroll
        for (int nt = 0; nt < 4; nt++)
            bf[nt] = *(const short8*)&Bs[(wcol + nt * 16 + l16) * 32 + quad * 8];
        #pragma unroll
        for (int nt = 0; nt < 4; nt++)
            #pragma unroll
            for (int mt = 0; mt < 4; mt++)
                acc[mt][nt] = mfma_bf16(af[mt], bf[nt], acc[mt][nt]);
    }

    float* Cf = (float*)Cv;
    unsigned short* Cb = (unsigned short*)Cv;
    #pragma unroll
    for (int mt = 0; mt < 4; mt++) {
        #pragma unroll
        for (int r = 0; r < 4; r++) {
            const int row = row0 + wrow + mt * 16 + quad * 4 + r;
            #pragma unroll
            for (int nt = 0; nt < 4; nt++) {
                const int col = col0 + wcol + nt * 16 + l16;
                const size_t idx = (size_t)row * N + col;
                const float v = acc[mt][nt][r];
                if (EPI == 0) {
                    Cb[idx] = f2bf(v);
                } else if (EPI == 1) {
                    Cf[idx] = v + bias[col];
                } else if (EPI == 2) {
                    float t = v + bias[col];
                    Cb[idx] = f2bf(0.5f * t * (1.f + erff(t * 0.70710678118654752f)));
                } else if (EPI == 3) {
                    float t = v + bias[col];
                    Cf[idx] = res[idx] + mod[(size_t)row * MODD + 1024 + col] * t;
                } else if (EPI == 4) {
                    float t = v + bias[col];
                    Cf[idx] = Cf[idx] + mod[(size_t)row * MODD + 2560 + col] * t;
                }
            }
        }
    }
}

// ---------------------------------------------------------------------------
// adaLN: dst(bf16)[n,:] = LN(src[n,:])*(1+mod[n,scale:+512]) + mod[n,shift:+512]
// ---------------------------------------------------------------------------
__global__ __launch_bounds__(256) void adaln_ln(
    const float* __restrict__ src, const float* __restrict__ mod,
    unsigned short* __restrict__ dst, int shift_off, int scale_off)
{
    const int n = blockIdx.x;
    const int tid = threadIdx.x;
    const float* xr = src + (size_t)n * DIMD;
    float v0 = xr[tid], v1 = xr[tid + 256];
    float s = v0 + v1;
    float q = v0 * v0 + v1 * v1;
    #pragma unroll
    for (int o = 32; o > 0; o >>= 1) {
        s += __shfl_down(s, o);
        q += __shfl_down(q, o);
    }
    __shared__ float sh[8];
    __shared__ float mu_sh, rs_sh;
    const int wid = tid >> 6, lane = tid & 63;
    if (lane == 0) { sh[wid] = s; sh[wid + 4] = q; }
    __syncthreads();
    if (tid == 0) {
        float S = sh[0] + sh[1] + sh[2] + sh[3];
        float Q = sh[4] + sh[5] + sh[6] + sh[7];
        float mu = S * (1.f / DIMD);
        float var = Q * (1.f / DIMD) - mu * mu;
        mu_sh = mu;
        rs_sh = rsqrtf(var + LNEPS);
    }
    __syncthreads();
    const float mu = mu_sh, rs = rs_sh;
    const float* mrow = mod + (size_t)n * MODD;
    const size_t o0 = (size_t)n * DIMD + tid;
    dst[o0]       = f2bf((v0 - mu) * rs * (1.f + mrow[scale_off + tid])       + mrow[shift_off + tid]);
    dst[o0 + 256] = f2bf((v1 - mu) * rs * (1.f + mrow[scale_off + tid + 256]) + mrow[shift_off + tid + 256]);
}

// ---------------------------------------------------------------------------
// MFMA flash attention (bf16 in/out, fp32 accumulate), causal.
// qkv: [NTOK,1536] bf16 (q/k/v at +0/+512/+1024, inner h*64+d). out bf16 [NTOK,512].
// Grid (T/128, H, B), 4 waves; wave = 32 q rows (2 m-tiles). K-tiles of 64.
// ---------------------------------------------------------------------------
__global__ __launch_bounds__(256) void attn_mfma(
    const unsigned short* __restrict__ qkv, unsigned short* __restrict__ outb)
{
    __shared__ unsigned short Kt[64][72];     // K[kpos][d], +8 pad
    __shared__ unsigned short Vt[64][72];     // V^T: Vt[d][kpos]
    __shared__ unsigned short Ps[4][32][72];  // per-wave P[q][kpos]

    const int qi = (TT / 128 - 1) - blockIdx.x;   // long blocks first
    const int h = blockIdx.y, b = blockIdx.z;
    const int tid = threadIdx.x;
    const int w = tid >> 6;
    const int lane = tid & 63;
    const int quad = lane >> 4;
    const int l16 = lane & 15;

    const int qw = qi * 128 + w * 32;
    const size_t tokbase = (size_t)b * TT;

    // Q fragments (bf16 direct)
    short8 qf[2][2];
    #pragma unroll
    for (int mt = 0; mt < 2; mt++) {
        const unsigned short* qp = qkv + (tokbase + qw + mt * 16 + l16) * 1536 + h * 64 + quad * 8;
        qf[mt][0] = *(const short8*)qp;
        qf[mt][1] = *(const short8*)(qp + 32);
    }

    f32x4 Oa[2][4];
    float mrow[2][4], lrow[2][4];
    #pragma unroll
    for (int mt = 0; mt < 2; mt++) {
        #pragma unroll
        for (int dt = 0; dt < 4; dt++) Oa[mt][dt] = (f32x4){0.f, 0.f, 0.f, 0.f};
        #pragma unroll
        for (int r = 0; r < 4; r++) { mrow[mt][r] = -INFINITY; lrow[mt][r] = 0.f; }
    }

    const int nkt = qi * 2 + 2;
    for (int kt = 0; kt < nkt; kt++) {
        // stage K tile (16B copies)
        #pragma unroll
        for (int it = 0; it < 2; it++) {
            const int i = tid + it * 256;           // 0..511
            const int kk = i >> 3, c = (i & 7) << 3;
            *(short8*)&Kt[kk][c] =
                *(const short8*)&qkv[(tokbase + kt * 64 + kk) * 1536 + 512 + h * 64 + c];
        }
        // stage V transposed (pack k,k+1 pairs into dwords)
        {
            const int k0 = (tid & 31) << 1;
            const int dbase = (tid >> 5) << 2;
            #pragma unroll
            for (int p = 0; p < 2; p++) {
                const int d0 = p * 32 + dbase;
                const unsigned short* vp =
                    qkv + (tokbase + kt * 64 + k0) * 1536 + 1024 + h * 64 + d0;
                short4v va = *(const short4v*)vp;
                short4v vb = *(const short4v*)(vp + 1536);
                *(unsigned*)&Vt[d0 + 0][k0] = (unsigned short)va[0] | ((unsigned)(unsigned short)vb[0] << 16);
                *(unsigned*)&Vt[d0 + 1][k0] = (unsigned short)va[1] | ((unsigned)(unsigned short)vb[1] << 16);
                *(unsigned*)&Vt[d0 + 2][k0] = (unsigned short)va[2] | ((unsigned)(unsigned short)vb[2] << 16);
                *(unsigned*)&Vt[d0 + 3][k0] = (unsigned short)va[3] | ((unsigned)(unsigned short)vb[3] << 16);
            }
        }
        __syncthreads();

        if (kt * 64 <= qw + 31) {
            // S = Q K^T
            f32x4 sacc[2][4];
            #pragma unroll
            for (int mt = 0; mt < 2; mt++)
                #pragma unroll
                for (int nt = 0; nt < 4; nt++) sacc[mt][nt] = (f32x4){0.f, 0.f, 0.f, 0.f};
            #pragma unroll
            for (int nt = 0; nt < 4; nt++) {
                const short8 kf0 = *(const short8*)&Kt[nt * 16 + l16][quad * 8];
                const short8 kf1 = *(const short8*)&Kt[nt * 16 + l16][32 + quad * 8];
                #pragma unroll
                for (int mt = 0; mt < 2; mt++) {
                    sacc[mt][nt] = mfma_bf16(qf[mt][0], kf0, sacc[mt][nt]);
                    sacc[mt][nt] = mfma_bf16(qf[mt][1], kf1, sacc[mt][nt]);
                }
            }
            #pragma unroll
            for (int mt = 0; mt < 2; mt++)
                #pragma unroll
                for (int nt = 0; nt < 4; nt++) sacc[mt][nt] *= 0.125f;

            // mask + online softmax + write P
            #pragma unroll
            for (int mt = 0; mt < 2; mt++) {
                const int qb = qw + mt * 16;
                if (kt * 64 + 63 > qb) {
                    #pragma unroll
                    for (int nt = 0; nt < 4; nt++) {
                        const int kg = kt * 64 + nt * 16 + l16;
                        #pragma unroll
                        for (int r = 0; r < 4; r++)
                            if (kg > qb + quad * 4 + r) sacc[mt][nt][r] = -INFINITY;
                    }
                }
                #pragma unroll
                for (int r = 0; r < 4; r++) {
                    float tm = fmaxf(fmaxf(sacc[mt][0][r], sacc[mt][1][r]),
                                     fmaxf(sacc[mt][2][r], sacc[mt][3][r]));
                    tm = fmaxf(tm, __shfl_xor(tm, 1));
                    tm = fmaxf(tm, __shfl_xor(tm, 2));
                    tm = fmaxf(tm, __shfl_xor(tm, 4));
                    tm = fmaxf(tm, __shfl_xor(tm, 8));
                    const float mn = fmaxf(mrow[mt][r], tm);
                    const float alpha = __expf(mrow[mt][r] - mn);
                    mrow[mt][r] = mn;
                    float p0 = __expf(sacc[mt][0][r] - mn);
                    float p1 = __expf(sacc[mt][1][r] - mn);
                    float p2 = __expf(sacc[mt][2][r] - mn);
                    float p3 = __expf(sacc[mt][3][r] - mn);
                    float ts = p0 + p1 + p2 + p3;
                    ts += __shfl_xor(ts, 1);
                    ts += __shfl_xor(ts, 2);
                    ts += __shfl_xor(ts, 4);
                    ts += __shfl_xor(ts, 8);
                    lrow[mt][r] = lrow[mt][r] * alpha + ts;
                    #pragma unroll
                    for (int dt = 0; dt < 4; dt++) Oa[mt][dt][r] *= alpha;
                    const int prow = mt * 16 + quad * 4 + r;
                    Ps[w][prow][l16]      = f2bf(p0);
                    Ps[w][prow][16 + l16] = f2bf(p1);
                    Ps[w][prow][32 + l16] = f2bf(p2);
                    Ps[w][prow][48 + l16] = f2bf(p3);
                }
            }
            __threadfence_block();  // intra-wave LDS RAW ordering
            // O += P V
            short8 pf[2][2];
            #pragma unroll
            for (int mt = 0; mt < 2; mt++) {
                pf[mt][0] = *(const short8*)&Ps[w][mt * 16 + l16][quad * 8];
                pf[mt][1] = *(const short8*)&Ps[w][mt * 16 + l16][32 + quad * 8];
            }
            #pragma unroll
            for (int dt = 0; dt < 4; dt++) {
                const short8 vf0 = *(const short8*)&Vt[dt * 16 + l16][quad * 8];
                const short8 vf1 = *(const short8*)&Vt[dt * 16 + l16][32 + quad * 8];
                #pragma unroll
                for (int mt = 0; mt < 2; mt++) {
                    Oa[mt][dt] = mfma_bf16(pf[mt][0], vf0, Oa[mt][dt]);
                    Oa[mt][dt] = mfma_bf16(pf[mt][1], vf1, Oa[mt][dt]);
                }
            }
        }
        __syncthreads();
    }

    #pragma unroll
    for (int mt = 0; mt < 2; mt++) {
        float inv[4];
        #pragma unroll
        for (int r = 0; r < 4; r++) inv[r] = 1.f / lrow[mt][r];
        #pragma unroll
        for (int dt = 0; dt < 4; dt++) {
            #pragma unroll
            for (int r = 0; r < 4; r++) {
                outb[(tokbase + qw + mt * 16 + quad * 4 + r) * DIMD + h * 64 + dt * 16 + l16]
                    = f2bf(Oa[mt][dt][r] * inv[r]);
            }
        }
    }
}

// ---------------------------------------------------------------------------
extern "C" void kernel_launch(void* const* d_in, const int* in_sizes, int n_in,
                              void* d_out, int out_size, void* d_ws, size_t ws_size,
                              hipStream_t stream)
{
    (void)in_sizes; (void)n_in; (void)out_size; (void)ws_size;

    const float* x    = (const float*)d_in[0];
    const float* aemb = (const float*)d_in[1];
    const float* Wqkv = (const float*)d_in[3];
    const float* Wout = (const float*)d_in[4];
    const float* bout = (const float*)d_in[5];
    const float* W1   = (const float*)d_in[6];
    const float* b1   = (const float*)d_in[7];
    const float* W2   = (const float*)d_in[8];
    const float* b2   = (const float*)d_in[9];
    const float* Wmod = (const float*)d_in[10];
    const float* bmod = (const float*)d_in[11];

    float* out = (float*)d_out;

    // workspace layout (bytes)
    char* p = (char*)d_ws;
    float* modw = (float*)p;            p += (size_t)NTOK * MODD * 4;   // 100.7 MB
    unsigned short* h12  = (unsigned short*)p; p += (size_t)NTOK * DIMD * 2;
    unsigned short* qkvb = (unsigned short*)p; p += (size_t)NTOK * 1536 * 2;
    unsigned short* attw = (unsigned short*)p; p += (size_t)NTOK * DIMD * 2;
    unsigned short* hid  = qkvb;        // reuses qkvb+attw (8192*2048*2 exactly)
    unsigned short* sact = (unsigned short*)p; p += (size_t)NTOK * ADIMD * 2;
    unsigned short* wq = (unsigned short*)p;   p += (size_t)1536 * 512 * 2;
    unsigned short* wo = (unsigned short*)p;   p += (size_t)512 * 512 * 2;
    unsigned short* w1 = (unsigned short*)p;   p += (size_t)2048 * 512 * 2;
    unsigned short* w2 = (unsigned short*)p;   p += (size_t)512 * 2048 * 2;
    unsigned short* wm = (unsigned short*)p;   p += (size_t)3072 * 256 * 2;

    // 0) dtype conversions
    cvt_bf16<0><<<(1536 * 512 / 4 + 255) / 256, 256, 0, stream>>>(Wqkv, wq, 1536 * 512 / 4);
    cvt_bf16<0><<<(512 * 512 / 4 + 255) / 256, 256, 0, stream>>>(Wout, wo, 512 * 512 / 4);
    cvt_bf16<0><<<(2048 * 512 / 4 + 255) / 256, 256, 0, stream>>>(W1, w1, 2048 * 512 / 4);
    cvt_bf16<0><<<(512 * 2048 / 4 + 255) / 256, 256, 0, stream>>>(W2, w2, 512 * 2048 / 4);
    cvt_bf16<0><<<(3072 * 256 / 4 + 255) / 256, 256, 0, stream>>>(Wmod, wm, 3072 * 256 / 4);
    cvt_bf16<1><<<(NTOK * ADIMD / 4 + 255) / 256, 256, 0, stream>>>(aemb, sact, NTOK * ADIMD / 4);

    // 1) mod = silu(action_emb) @ Wmod^T + bmod  (fp32 out)
    gemm_bf16<1><<<dim3(MODD / 128, NTOK / 128), 256, 0, stream>>>(
        sact, wm, bmod, nullptr, nullptr, NTOK, MODD, ADIMD, modw);

    // 2) h1 = LN(x)*(1+scale1)+shift1  (bf16 out)
    adaln_ln<<<NTOK, 256, 0, stream>>>(x, modw, h12, 0, 512);

    // 3) qkv = h1 @ Wqkv^T  (bf16 out)
    gemm_bf16<0><<<dim3(1536 / 128, NTOK / 128), 256, 0, stream>>>(
        h12, wq, nullptr, nullptr, nullptr, NTOK, 1536, DIMD, qkvb);

    // 4) attention (bf16 flash MFMA)
    attn_mfma<<<dim3(TT / 128, HH, BB), 256, 0, stream>>>(qkvb, attw);

    // 5) x_mid = x + gate1 * (attw @ Wout^T + bout)  (fp32 out -> d_out)
    gemm_bf16<3><<<dim3(DIMD / 128, NTOK / 128), 256, 0, stream>>>(
        attw, wo, bout, x, modw, NTOK, DIMD, DIMD, out);

    // 6) h2 = LN(x_mid)*(1+scale2)+shift2  (bf16 out)
    adaln_ln<<<NTOK, 256, 0, stream>>>(out, modw, h12, 1536, 2048);

    // 7) hid = gelu(h2 @ W1^T + b1)  (bf16 out)
    gemm_bf16<2><<<dim3(MLPD / 128, NTOK / 128), 256, 0, stream>>>(
        h12, w1, b1, nullptr, nullptr, NTOK, MLPD, DIMD, hid);

    // 8) d_out = x_mid + gate2 * (hid @ W2^T + b2)  (fp32 RMW)
    gemm_bf16<4><<<dim3(DIMD / 128, NTOK / 128), 256, 0, stream>>>(
        hid, w2, b2, nullptr, modw, NTOK, DIMD, MLPD, out);
}

// Round 4
// 352.503 us; speedup vs baseline: 5.2714x; 1.2273x over previous
//
#include <hip/hip_runtime.h>
#include <math.h>
#include <stdint.h>

// Problem constants
#define BB 4
#define TT 2048
#define NTOK 8192        // B*T
#define DIMD 512
#define HH 8
#define DHH 64
#define MLPD 2048
#define ADIMD 256
#define MODD 3072        // 6*DIM
#define LNEPS 1e-5f
#define LOG2E_8 0.18033688011112042f   // log2(e)/8

typedef short short8 __attribute__((ext_vector_type(8)));
typedef unsigned short ushort4v __attribute__((ext_vector_type(4)));
typedef __bf16 bf16x8 __attribute__((ext_vector_type(8)));
typedef float f32x4 __attribute__((ext_vector_type(4)));

static __device__ __forceinline__ unsigned short f2bf(float f) {
    union { float f; unsigned u; } v; v.f = f;
    unsigned r = v.u + 0x7fffu + ((v.u >> 16) & 1u);
    return (unsigned short)(r >> 16);
}
static __device__ __forceinline__ float bf2f(unsigned short u) {
    union { unsigned u; float f; } v; v.u = (unsigned)u << 16; return v.f;
}

static __device__ __forceinline__ f32x4 mfma_bf16(short8 a, short8 b, f32x4 c) {
    return __builtin_amdgcn_mfma_f32_16x16x32_bf16(
        __builtin_bit_cast(bf16x8, a), __builtin_bit_cast(bf16x8, b), c, 0, 0, 0);
}

// async global->LDS, 16B per lane; lds dest must be wave-uniform base (+lane*16)
static __device__ __forceinline__ void gld16(const void* g, const void* l) {
    __builtin_amdgcn_global_load_lds(
        (const __attribute__((address_space(1))) unsigned*)(unsigned long long)(uintptr_t)g,
        (__attribute__((address_space(3))) unsigned*)(unsigned)(uintptr_t)l,
        16, 0, 0);
}

// ---------------------------------------------------------------------------
// Merged fp32->bf16 conversion: 5 weights + silu(action_emb), one launch
// ---------------------------------------------------------------------------
struct CvtArgs {
    const float* s[6];
    unsigned short* d[6];
    int cum[7];   // cumulative n4 offsets
};
__global__ __launch_bounds__(256) void cvt_all(CvtArgs a)
{
    const int i = blockIdx.x * 256 + threadIdx.x;
    if (i >= a.cum[6]) return;
    int seg = 0;
    #pragma unroll
    for (int k = 1; k < 6; k++) seg += (i >= a.cum[k]);
    const int off = i - a.cum[seg];
    float4 v = ((const float4*)a.s[seg])[off];
    if (seg == 5) {   // silu for action_emb
        v.x = v.x / (1.f + __expf(-v.x));
        v.y = v.y / (1.f + __expf(-v.y));
        v.z = v.z / (1.f + __expf(-v.z));
        v.w = v.w / (1.f + __expf(-v.w));
    }
    ushort4v o = { f2bf(v.x), f2bf(v.y), f2bf(v.z), f2bf(v.w) };
    ((ushort4v*)a.d[seg])[off] = o;
}

// ---------------------------------------------------------------------------
// bf16 MFMA NT GEMM: C[m,n] = epi( sum_k A[m,k]*B[n,k] )
// A: MxK bf16, B: NxK bf16 (both row-major). Tile 128 x BN, BK=32, 4 waves.
// BN=128: wave = 64x64 (4x4 MFMA grid). BN=64: wave = 32x64 (2x4 grid).
// EPI: 0 = bf16 store
//      2 = bf16 store gelu_exact(acc + bias[n])
//      3 = fp32 store res[m,n] + mod[m*3072+1024+n]*(acc+bias[n])
//      4 = fp32 RMW    C[m,n] + mod[m*3072+2560+n]*(acc+bias[n])
//      5 = bf16 store acc + bias[n]
// ---------------------------------------------------------------------------
template<int EPI, int BN>
__global__ __launch_bounds__(256) void gemm_bf16(
    const unsigned short* __restrict__ A, const unsigned short* __restrict__ Bw,
    const float* __restrict__ bias, const float* __restrict__ res,
    const unsigned short* __restrict__ mod,
    int M, int N, int K,
    void* __restrict__ Cv)
{
    constexpr int MT = (BN == 128) ? 4 : 2;
    __shared__ unsigned short As[128 * 32];
    __shared__ unsigned short Bs[BN * 32];

    const int tid = threadIdx.x;
    const int w = tid >> 6, lane = tid & 63;
    const int quad = lane >> 4, l16 = lane & 15;
    const int wrow = (BN == 128) ? (w >> 1) * 64 : w * 32;
    const int wcol = (BN == 128) ? (w & 1) * 64 : 0;
    const int row0 = blockIdx.y * 128, col0 = blockIdx.x * BN;

    const int lrow = lane >> 2;        // 0..15 row within 16-row chunk
    const int lch  = (lane & 3) * 8;   // element offset of 16B chunk

    f32x4 acc[MT][4];
    #pragma unroll
    for (int i = 0; i < MT; i++)
        #pragma unroll
        for (int j = 0; j < 4; j++) acc[i][j] = (f32x4){0.f, 0.f, 0.f, 0.f};

    for (int k0 = 0; k0 < K; k0 += 32) {
        __syncthreads();   // previous iter's reads done
        #pragma unroll
        for (int c = 0; c < 2; c++) {
            const int r = w * 16 + c * 64;   // wave-uniform
            gld16(&A[(size_t)(row0 + r + lrow) * K + k0 + lch], &As[r * 32]);
            if (BN == 128)
                gld16(&Bw[(size_t)(col0 + r + lrow) * K + k0 + lch], &Bs[r * 32]);
        }
        if (BN == 64) {
            const int r = w * 16;
            gld16(&Bw[(size_t)(col0 + r + lrow) * K + k0 + lch], &Bs[r * 32]);
        }
        __syncthreads();   // staging visible

        short8 af[MT], bf[4];
        #pragma unroll
        for (int mt = 0; mt < MT; mt++)
            af[mt] = *(const short8*)&As[(wrow + mt * 16 + l16) * 32 + quad * 8];
        #pragma unroll
        for (int nt = 0; nt < 4; nt++)
            bf[nt] = *(const short8*)&Bs[(wcol + nt * 16 + l16) * 32 + quad * 8];
        #pragma unroll
        for (int nt = 0; nt < 4; nt++)
            #pragma unroll
            for (int mt = 0; mt < MT; mt++)
                acc[mt][nt] = mfma_bf16(af[mt], bf[nt], acc[mt][nt]);
    }

    float* Cf = (float*)Cv;
    unsigned short* Cb = (unsigned short*)Cv;
    #pragma unroll
    for (int mt = 0; mt < MT; mt++) {
        #pragma unroll
        for (int r = 0; r < 4; r++) {
            const int row = row0 + wrow + mt * 16 + quad * 4 + r;
            #pragma unroll
            for (int nt = 0; nt < 4; nt++) {
                const int col = col0 + wcol + nt * 16 + l16;
                const size_t idx = (size_t)row * N + col;
                const float v = acc[mt][nt][r];
                if (EPI == 0) {
                    Cb[idx] = f2bf(v);
                } else if (EPI == 2) {
                    float t = v + bias[col];
                    Cb[idx] = f2bf(0.5f * t * (1.f + erff(t * 0.70710678118654752f)));
                } else if (EPI == 3) {
                    float t = v + bias[col];
                    Cf[idx] = res[idx] + bf2f(mod[(size_t)row * MODD + 1024 + col]) * t;
                } else if (EPI == 4) {
                    float t = v + bias[col];
                    Cf[idx] = Cf[idx] + bf2f(mod[(size_t)row * MODD + 2560 + col]) * t;
                } else if (EPI == 5) {
                    Cb[idx] = f2bf(v + bias[col]);
                }
            }
        }
    }
}

// ---------------------------------------------------------------------------
// adaLN: dst(bf16)[n,:] = LN(src[n,:])*(1+mod[n,scale:+512]) + mod[n,shift:+512]
// mod is bf16.
// ---------------------------------------------------------------------------
__global__ __launch_bounds__(256) void adaln_ln(
    const float* __restrict__ src, const unsigned short* __restrict__ mod,
    unsigned short* __restrict__ dst, int shift_off, int scale_off)
{
    const int n = blockIdx.x;
    const int tid = threadIdx.x;
    const float* xr = src + (size_t)n * DIMD;
    float v0 = xr[tid], v1 = xr[tid + 256];
    float s = v0 + v1;
    float q = v0 * v0 + v1 * v1;
    #pragma unroll
    for (int o = 32; o > 0; o >>= 1) {
        s += __shfl_down(s, o);
        q += __shfl_down(q, o);
    }
    __shared__ float sh[8];
    __shared__ float mu_sh, rs_sh;
    const int wid = tid >> 6, lane = tid & 63;
    if (lane == 0) { sh[wid] = s; sh[wid + 4] = q; }
    __syncthreads();
    if (tid == 0) {
        float S = sh[0] + sh[1] + sh[2] + sh[3];
        float Q = sh[4] + sh[5] + sh[6] + sh[7];
        float mu = S * (1.f / DIMD);
        float var = Q * (1.f / DIMD) - mu * mu;
        mu_sh = mu;
        rs_sh = rsqrtf(var + LNEPS);
    }
    __syncthreads();
    const float mu = mu_sh, rs = rs_sh;
    const unsigned short* mrow = mod + (size_t)n * MODD;
    const size_t o0 = (size_t)n * DIMD + tid;
    dst[o0]       = f2bf((v0 - mu) * rs * (1.f + bf2f(mrow[scale_off + tid]))       + bf2f(mrow[shift_off + tid]));
    dst[o0 + 256] = f2bf((v1 - mu) * rs * (1.f + bf2f(mrow[scale_off + tid + 256])) + bf2f(mrow[shift_off + tid + 256]));
}

// ---------------------------------------------------------------------------
// MFMA flash attention v2 (bf16, fp32 acc), causal, transposed-score scheme.
// qkv: [NTOK,1536] bf16 (q/k/v at +0/+512/+1024, inner h*64+d). out bf16 [NTOK,512].
// Grid (T/128, H, B), 4 waves; wave = 32 q rows (2 n-tiles of 16). K-tile = 128.
// S^T = K·Q^T  -> C-layout col=lane&15 = q-row  => softmax nearly shfl-free.
// P stored as P[q][k] in LDS; O^T = V^T·P^T, col = q-row again.
// Every tile kt < qi is full (no divergence); only kt==qi masks per element.
// ---------------------------------------------------------------------------
__global__ __launch_bounds__(256, 2) void attn_mfma(
    const unsigned short* __restrict__ qkv, unsigned short* __restrict__ outb)
{
    __shared__ unsigned short Kt[128][72];     // K[kpos][d], +8 pad
    __shared__ unsigned short Vt[64][136];     // V^T: Vt[d][kpos], +8 pad
    __shared__ unsigned short Ps[4][32][136];  // per-wave P[q][kpos]

    const int qi = (TT / 128 - 1) - blockIdx.x;   // long blocks first
    const int h = blockIdx.y, b = blockIdx.z;
    const int tid = threadIdx.x;
    const int w = tid >> 6;
    const int lane = tid & 63;
    const int quad = lane >> 4;
    const int l16 = lane & 15;

    const int qw = qi * 128 + w * 32;
    const size_t tokbase = (size_t)b * TT;

    // Q fragments (B operand of S^T = K·Q^T); fold log2(e)/8 into the bf16
    short8 qf[2][2];
    #pragma unroll
    for (int nt = 0; nt < 2; nt++) {
        const unsigned short* qp = qkv + (tokbase + qw + nt * 16 + l16) * 1536 + h * 64 + quad * 8;
        #pragma unroll
        for (int hd = 0; hd < 2; hd++) {
            short8 raw = *(const short8*)(qp + hd * 32);
            short8 f;
            #pragma unroll
            for (int j = 0; j < 8; j++)
                f[j] = (short)f2bf(bf2f((unsigned short)raw[j]) * LOG2E_8);
            qf[nt][hd] = f;
        }
    }

    f32x4 Oa[4][2];   // [d-tile][q-tile]; col=lane&15=q, row=quad*4+r=d
    float mrun[2] = {-INFINITY, -INFINITY}, lrun[2] = {0.f, 0.f};
    #pragma unroll
    for (int mt = 0; mt < 4; mt++)
        #pragma unroll
        for (int nt = 0; nt < 2; nt++) Oa[mt][nt] = (f32x4){0.f, 0.f, 0.f, 0.f};

    const int nkt = qi + 1;
    const int vk0 = (tid & 63) * 2;        // k-pair this thread transposes
    const int vdb = (tid >> 6) * 8;        // d-chunk base

    short8 kpre[4], vpre[4];
    auto prefetchKV = [&](int kt) {
        const unsigned short* kb = qkv + (tokbase + (size_t)kt * 128) * 1536 + 512 + h * 64;
        #pragma unroll
        for (int it = 0; it < 4; it++) {
            const int i = tid + it * 256;
            kpre[it] = *(const short8*)(kb + (size_t)(i >> 3) * 1536 + (i & 7) * 8);
        }
        const unsigned short* vb = qkv + (tokbase + (size_t)kt * 128 + vk0) * 1536 + 1024 + h * 64;
        #pragma unroll
        for (int p = 0; p < 2; p++) {
            vpre[2 * p]     = *(const short8*)(vb + p * 32 + vdb);
            vpre[2 * p + 1] = *(const short8*)(vb + 1536 + p * 32 + vdb);
        }
    };
    auto storeKV = [&]() {
        #pragma unroll
        for (int it = 0; it < 4; it++) {
            const int i = tid + it * 256;
            *(short8*)&Kt[i >> 3][(i & 7) * 8] = kpre[it];
        }
        #pragma unroll
        for (int p = 0; p < 2; p++)
            #pragma unroll
            for (int j = 0; j < 8; j++) {
                const int d = p * 32 + vdb + j;
                *(unsigned*)&Vt[d][vk0] =
                    (unsigned)(unsigned short)vpre[2 * p][j]
                    | ((unsigned)(unsigned short)vpre[2 * p + 1][j] << 16);
            }
    };

    prefetchKV(0);
    storeKV();
    __syncthreads();

    for (int kt = 0; kt < nkt; kt++) {
        const bool haveNext = (kt + 1 < nkt);
        if (haveNext) prefetchKV(kt + 1);   // loads in flight during compute

        // ---- S^T = K·Q^T ----  A = K (rows = kpos), B = Q^T
        short8 af[8][2];
        #pragma unroll
        for (int mk = 0; mk < 8; mk++) {
            af[mk][0] = *(const short8*)&Kt[mk * 16 + l16][quad * 8];
            af[mk][1] = *(const short8*)&Kt[mk * 16 + l16][32 + quad * 8];
        }
        #pragma unroll
        for (int nt = 0; nt < 2; nt++) {
            f32x4 st[8];
            #pragma unroll
            for (int mk = 0; mk < 8; mk++) {
                st[mk] = (f32x4){0.f, 0.f, 0.f, 0.f};
                st[mk] = mfma_bf16(af[mk][0], qf[nt][0], st[mk]);
                st[mk] = mfma_bf16(af[mk][1], qf[nt][1], st[mk]);
            }
            if (kt == qi) {   // diagonal tile: causal mask
                const int qrel = w * 32 + nt * 16 + l16;
                #pragma unroll
                for (int mk = 0; mk < 8; mk++)
                    #pragma unroll
                    for (int r = 0; r < 4; r++)
                        if (mk * 16 + quad * 4 + r > qrel) st[mk][r] = -INFINITY;
            }
            // per-lane softmax (q = fixed per lane); cross-quad reduce only
            float tm = -INFINITY;
            #pragma unroll
            for (int mk = 0; mk < 8; mk++)
                #pragma unroll
                for (int r = 0; r < 4; r++) tm = fmaxf(tm, st[mk][r]);
            tm = fmaxf(tm, __shfl_xor(tm, 16));
            tm = fmaxf(tm, __shfl_xor(tm, 32));
            const float mn = fmaxf(mrun[nt], tm);
            const float alpha = __builtin_amdgcn_exp2f(mrun[nt] - mn);
            mrun[nt] = mn;
            float ts = 0.f;
            #pragma unroll
            for (int mk = 0; mk < 8; mk++) {
                const float p0 = __builtin_amdgcn_exp2f(st[mk][0] - mn);
                const float p1 = __builtin_amdgcn_exp2f(st[mk][1] - mn);
                const float p2 = __builtin_amdgcn_exp2f(st[mk][2] - mn);
                const float p3 = __builtin_amdgcn_exp2f(st[mk][3] - mn);
                ts += (p0 + p1) + (p2 + p3);
                const unsigned long long pk =
                    (unsigned long long)f2bf(p0)
                    | ((unsigned long long)f2bf(p1) << 16)
                    | ((unsigned long long)f2bf(p2) << 32)
                    | ((unsigned long long)f2bf(p3) << 48);
                *(unsigned long long*)&Ps[w][nt * 16 + l16][mk * 16 + quad * 4] = pk;
            }
            ts += __shfl_xor(ts, 16);
            ts += __shfl_xor(ts, 32);
            lrun[nt] = lrun[nt] * alpha + ts;
            #pragma unroll
            for (int mt = 0; mt < 4; mt++) Oa[mt][nt] *= alpha;
        }
        __threadfence_block();   // own Ps stores -> reads ordering

        // ---- O^T += V^T·P^T ----  A = V^T, B = P^T (read from P[q][k])
        short8 pf0[4], pf1[4];
        #pragma unroll
        for (int kc = 0; kc < 4; kc++) {
            pf0[kc] = *(const short8*)&Ps[w][l16][kc * 32 + quad * 8];
            pf1[kc] = *(const short8*)&Ps[w][16 + l16][kc * 32 + quad * 8];
        }
        #pragma unroll
        for (int mt = 0; mt < 4; mt++)
            #pragma unroll
            for (int kc = 0; kc < 4; kc++) {
                const short8 vf = *(const short8*)&Vt[mt * 16 + l16][kc * 32 + quad * 8];
                Oa[mt][0] = mfma_bf16(vf, pf0[kc], Oa[mt][0]);
                Oa[mt][1] = mfma_bf16(vf, pf1[kc], Oa[mt][1]);
            }

        __syncthreads();            // all LDS reads of tile kt done
        if (haveNext) storeKV();    // implicit vmcnt waits on prefetched regs
        __syncthreads();            // staging visible
    }

    // ---- epilogue: O /= l ----  lane owns q-row (per n-tile)
    #pragma unroll
    for (int nt = 0; nt < 2; nt++) {
        const float inv = 1.f / lrun[nt];
        const size_t tok = tokbase + qw + nt * 16 + l16;
        #pragma unroll
        for (int mt = 0; mt < 4; mt++) {
            const unsigned long long pk =
                (unsigned long long)f2bf(Oa[mt][nt][0] * inv)
                | ((unsigned long long)f2bf(Oa[mt][nt][1] * inv) << 16)
                | ((unsigned long long)f2bf(Oa[mt][nt][2] * inv) << 32)
                | ((unsigned long long)f2bf(Oa[mt][nt][3] * inv) << 48);
            *(unsigned long long*)&outb[tok * DIMD + h * 64 + mt * 16 + quad * 4] = pk;
        }
    }
}

// ---------------------------------------------------------------------------
extern "C" void kernel_launch(void* const* d_in, const int* in_sizes, int n_in,
                              void* d_out, int out_size, void* d_ws, size_t ws_size,
                              hipStream_t stream)
{
    (void)in_sizes; (void)n_in; (void)out_size; (void)ws_size;

    const float* x    = (const float*)d_in[0];
    const float* aemb = (const float*)d_in[1];
    const float* Wqkv = (const float*)d_in[3];
    const float* Wout = (const float*)d_in[4];
    const float* bout = (const float*)d_in[5];
    const float* W1   = (const float*)d_in[6];
    const float* b1   = (const float*)d_in[7];
    const float* W2   = (const float*)d_in[8];
    const float* b2   = (const float*)d_in[9];
    const float* Wmod = (const float*)d_in[10];
    const float* bmod = (const float*)d_in[11];

    float* out = (float*)d_out;

    // workspace layout
    char* p = (char*)d_ws;
    unsigned short* modw = (unsigned short*)p; p += (size_t)NTOK * MODD * 2;   // bf16 mod
    unsigned short* h12  = (unsigned short*)p; p += (size_t)NTOK * DIMD * 2;
    unsigned short* qkvb = (unsigned short*)p; p += (size_t)NTOK * 1536 * 2;
    unsigned short* attw = (unsigned short*)p; p += (size_t)NTOK * DIMD * 2;
    unsigned short* hid  = qkvb;        // reuses qkvb+attw (8192*2048*2 exactly)
    unsigned short* sact = (unsigned short*)p; p += (size_t)NTOK * ADIMD * 2;
    unsigned short* wq = (unsigned short*)p;   p += (size_t)1536 * 512 * 2;
    unsigned short* wo = (unsigned short*)p;   p += (size_t)512 * 512 * 2;
    unsigned short* w1 = (unsigned short*)p;   p += (size_t)2048 * 512 * 2;
    unsigned short* w2 = (unsigned short*)p;   p += (size_t)512 * 2048 * 2;
    unsigned short* wm = (unsigned short*)p;   p += (size_t)3072 * 256 * 2;

    // 0) all dtype conversions in one launch
    CvtArgs ca;
    ca.s[0] = Wqkv; ca.d[0] = wq;
    ca.s[1] = Wout; ca.d[1] = wo;
    ca.s[2] = W1;   ca.d[2] = w1;
    ca.s[3] = W2;   ca.d[3] = w2;
    ca.s[4] = Wmod; ca.d[4] = wm;
    ca.s[5] = aemb; ca.d[5] = sact;   // silu applied
    const int n4s[6] = {1536 * 512 / 4, 512 * 512 / 4, 2048 * 512 / 4,
                        512 * 2048 / 4, 3072 * 256 / 4, NTOK * ADIMD / 4};
    ca.cum[0] = 0;
    for (int i = 0; i < 6; i++) ca.cum[i + 1] = ca.cum[i] + n4s[i];
    cvt_all<<<(ca.cum[6] + 255) / 256, 256, 0, stream>>>(ca);

    // 1) mod = silu(action_emb) @ Wmod^T + bmod  (bf16 out)
    gemm_bf16<5, 128><<<dim3(MODD / 128, NTOK / 128), 256, 0, stream>>>(
        sact, wm, bmod, nullptr, nullptr, NTOK, MODD, ADIMD, modw);

    // 2) h1 = LN(x)*(1+scale1)+shift1  (bf16 out)
    adaln_ln<<<NTOK, 256, 0, stream>>>(x, modw, h12, 0, 512);

    // 3) qkv = h1 @ Wqkv^T  (bf16 out)
    gemm_bf16<0, 128><<<dim3(1536 / 128, NTOK / 128), 256, 0, stream>>>(
        h12, wq, nullptr, nullptr, nullptr, NTOK, 1536, DIMD, qkvb);

    // 4) attention (bf16 flash MFMA v2)
    attn_mfma<<<dim3(TT / 128, HH, BB), 256, 0, stream>>>(qkvb, attw);

    // 5) x_mid = x + gate1 * (attw @ Wout^T + bout)  (fp32 out -> d_out)
    gemm_bf16<3, 64><<<dim3(DIMD / 64, NTOK / 128), 256, 0, stream>>>(
        attw, wo, bout, x, modw, NTOK, DIMD, DIMD, out);

    // 6) h2 = LN(x_mid)*(1+scale2)+shift2  (bf16 out)
    adaln_ln<<<NTOK, 256, 0, stream>>>(out, modw, h12, 1536, 2048);

    // 7) hid = gelu(h2 @ W1^T + b1)  (bf16 out)
    gemm_bf16<2, 128><<<dim3(MLPD / 128, NTOK / 128), 256, 0, stream>>>(
        h12, w1, b1, nullptr, nullptr, NTOK, MLPD, DIMD, hid);

    // 8) d_out = x_mid + gate2 * (hid @ W2^T + b2)  (fp32 RMW)
    gemm_bf16<4, 64><<<dim3(DIMD / 64, NTOK / 128), 256, 0, stream>>>(
        hid, w2, b2, nullptr, modw, NTOK, DIMD, MLPD, out);
}

// Round 5
// 338.087 us; speedup vs baseline: 5.4961x; 1.0426x over previous
//
#include <hip/hip_runtime.h>
#include <math.h>
#include <stdint.h>

// Problem constants
#define BB 4
#define TT 2048
#define NTOK 8192        // B*T
#define DIMD 512
#define HH 8
#define DHH 64
#define MLPD 2048
#define ADIMD 256
#define MODD 3072        // 6*DIM
#define LNEPS 1e-5f
#define LOG2E_8 0.18033688011112042f   // log2(e)/8

typedef short short8 __attribute__((ext_vector_type(8)));
typedef unsigned short ushort4v __attribute__((ext_vector_type(4)));
typedef __bf16 bf16x8 __attribute__((ext_vector_type(8)));
typedef float f32x4 __attribute__((ext_vector_type(4)));

static __device__ __forceinline__ unsigned short f2bf(float f) {
    union { float f; unsigned u; } v; v.f = f;
    unsigned r = v.u + 0x7fffu + ((v.u >> 16) & 1u);
    return (unsigned short)(r >> 16);
}
static __device__ __forceinline__ float bf2f(unsigned short u) {
    union { unsigned u; float f; } v; v.u = (unsigned)u << 16; return v.f;
}

static __device__ __forceinline__ f32x4 mfma_bf16(short8 a, short8 b, f32x4 c) {
    return __builtin_amdgcn_mfma_f32_16x16x32_bf16(
        __builtin_bit_cast(bf16x8, a), __builtin_bit_cast(bf16x8, b), c, 0, 0, 0);
}

// ---------------------------------------------------------------------------
// Merged fp32->bf16 conversion: 5 weights + silu(action_emb), one launch
// ---------------------------------------------------------------------------
struct CvtArgs {
    const float* s[6];
    unsigned short* d[6];
    int cum[7];   // cumulative n4 offsets
};
__global__ __launch_bounds__(256) void cvt_all(CvtArgs a)
{
    const int i = blockIdx.x * 256 + threadIdx.x;
    if (i >= a.cum[6]) return;
    int seg = 0;
    #pragma unroll
    for (int k = 1; k < 6; k++) seg += (i >= a.cum[k]);
    const int off = i - a.cum[seg];
    float4 v = ((const float4*)a.s[seg])[off];
    if (seg == 5) {   // silu for action_emb
        v.x = v.x / (1.f + __expf(-v.x));
        v.y = v.y / (1.f + __expf(-v.y));
        v.z = v.z / (1.f + __expf(-v.z));
        v.w = v.w / (1.f + __expf(-v.w));
    }
    ushort4v o = { f2bf(v.x), f2bf(v.y), f2bf(v.z), f2bf(v.w) };
    ((ushort4v*)a.d[seg])[off] = o;
}

// ---------------------------------------------------------------------------
// bf16 MFMA NT GEMM, pipelined K-loop: C[m,n] = epi( sum_k A[m,k]*B[n,k] )
// A: MxK bf16, B: NxK bf16 (row-major). Tile 128 x BN, BK=64, 4 waves.
// Register-prefetch pipeline: global loads for k0+64 issue before the MFMAs
// of k0; ds_write (with its implicit vmcnt wait) lands after compute.
// BN=128: wave = 64x64 (4x4 MFMA grid). BN=64: wave = 32x64 (2x4 grid).
// EPI: 0 = bf16 store
//      2 = bf16 store gelu_exact(acc + bias[n])
//      3 = fp32 store res[m,n] + mod[m*3072+1024+n]*(acc+bias[n])
//      4 = fp32 RMW    C[m,n] + mod[m*3072+2560+n]*(acc+bias[n])
//      5 = bf16 store acc + bias[n]
// ---------------------------------------------------------------------------
template<int EPI, int BN>
__global__ __launch_bounds__(256) void gemm_bf16(
    const unsigned short* __restrict__ A, const unsigned short* __restrict__ Bw,
    const float* __restrict__ bias, const float* __restrict__ res,
    const unsigned short* __restrict__ mod,
    int M, int N, int K,
    void* __restrict__ Cv)
{
    constexpr int MT = (BN == 128) ? 4 : 2;   // per-wave m-tiles (of 16)
    constexpr int NPB = (BN == 128) ? 4 : 2;  // B staging passes per thread
    __shared__ unsigned short As[128 * 72];   // [row][k], stride 72 (bank-balanced)
    __shared__ unsigned short Bs[BN * 72];

    const int tid = threadIdx.x;
    const int w = tid >> 6, lane = tid & 63;
    const int quad = lane >> 4, l16 = lane & 15;
    const int wrow = (BN == 128) ? (w >> 1) * 64 : w * 32;
    const int wcol = (BN == 128) ? (w & 1) * 64 : 0;
    const int row0 = blockIdx.y * 128, col0 = blockIdx.x * BN;

    // staging map: chunk c = tid + p*256 -> row = c>>3, k-chunk = (c&7)*8
    const int srow = tid >> 3;          // 0..31
    const int skc  = (tid & 7) * 8;     // 0..56

    f32x4 acc[MT][4];
    #pragma unroll
    for (int i = 0; i < MT; i++)
        #pragma unroll
        for (int j = 0; j < 4; j++) acc[i][j] = (f32x4){0.f, 0.f, 0.f, 0.f};

    short8 pA[4], pB[NPB];
    auto prefetch = [&](int k0) {
        #pragma unroll
        for (int p = 0; p < 4; p++)
            pA[p] = *(const short8*)&A[(size_t)(row0 + srow + p * 32) * K + k0 + skc];
        #pragma unroll
        for (int p = 0; p < NPB; p++)
            pB[p] = *(const short8*)&Bw[(size_t)(col0 + srow + p * 32) * K + k0 + skc];
    };
    auto stage = [&]() {
        #pragma unroll
        for (int p = 0; p < 4; p++)
            *(short8*)&As[(srow + p * 32) * 72 + skc] = pA[p];
        #pragma unroll
        for (int p = 0; p < NPB; p++)
            *(short8*)&Bs[(srow + p * 32) * 72 + skc] = pB[p];
    };

    prefetch(0);
    stage();
    __syncthreads();

    for (int k0 = 0; k0 < K; k0 += 64) {
        const bool more = (k0 + 64 < K);
        if (more) prefetch(k0 + 64);    // loads in flight during MFMAs

        #pragma unroll
        for (int ks = 0; ks < 2; ks++) {
            short8 af[MT], bf[4];
            #pragma unroll
            for (int mt = 0; mt < MT; mt++)
                af[mt] = *(const short8*)&As[(wrow + mt * 16 + l16) * 72 + ks * 32 + quad * 8];
            #pragma unroll
            for (int nt = 0; nt < 4; nt++)
                bf[nt] = *(const short8*)&Bs[(wcol + nt * 16 + l16) * 72 + ks * 32 + quad * 8];
            #pragma unroll
            for (int nt = 0; nt < 4; nt++)
                #pragma unroll
                for (int mt = 0; mt < MT; mt++)
                    acc[mt][nt] = mfma_bf16(af[mt], bf[nt], acc[mt][nt]);
        }
        __syncthreads();                // all LDS reads of this tile done
        if (more) stage();              // vmcnt wait lands here, after compute
        __syncthreads();                // staging visible
    }

    float* Cf = (float*)Cv;
    unsigned short* Cb = (unsigned short*)Cv;
    #pragma unroll
    for (int mt = 0; mt < MT; mt++) {
        #pragma unroll
        for (int r = 0; r < 4; r++) {
            const int row = row0 + wrow + mt * 16 + quad * 4 + r;
            #pragma unroll
            for (int nt = 0; nt < 4; nt++) {
                const int col = col0 + wcol + nt * 16 + l16;
                const size_t idx = (size_t)row * N + col;
                const float v = acc[mt][nt][r];
                if (EPI == 0) {
                    Cb[idx] = f2bf(v);
                } else if (EPI == 2) {
                    float t = v + bias[col];
                    Cb[idx] = f2bf(0.5f * t * (1.f + erff(t * 0.70710678118654752f)));
                } else if (EPI == 3) {
                    float t = v + bias[col];
                    Cf[idx] = res[idx] + bf2f(mod[(size_t)row * MODD + 1024 + col]) * t;
                } else if (EPI == 4) {
                    float t = v + bias[col];
                    Cf[idx] = Cf[idx] + bf2f(mod[(size_t)row * MODD + 2560 + col]) * t;
                } else if (EPI == 5) {
                    Cb[idx] = f2bf(v + bias[col]);
                }
            }
        }
    }
}

// ---------------------------------------------------------------------------
// adaLN: dst(bf16)[n,:] = LN(src[n,:])*(1+mod[n,scale:+512]) + mod[n,shift:+512]
// ---------------------------------------------------------------------------
__global__ __launch_bounds__(256) void adaln_ln(
    const float* __restrict__ src, const unsigned short* __restrict__ mod,
    unsigned short* __restrict__ dst, int shift_off, int scale_off)
{
    const int n = blockIdx.x;
    const int tid = threadIdx.x;
    const float* xr = src + (size_t)n * DIMD;
    float v0 = xr[tid], v1 = xr[tid + 256];
    float s = v0 + v1;
    float q = v0 * v0 + v1 * v1;
    #pragma unroll
    for (int o = 32; o > 0; o >>= 1) {
        s += __shfl_down(s, o);
        q += __shfl_down(q, o);
    }
    __shared__ float sh[8];
    __shared__ float mu_sh, rs_sh;
    const int wid = tid >> 6, lane = tid & 63;
    if (lane == 0) { sh[wid] = s; sh[wid + 4] = q; }
    __syncthreads();
    if (tid == 0) {
        float S = sh[0] + sh[1] + sh[2] + sh[3];
        float Q = sh[4] + sh[5] + sh[6] + sh[7];
        float mu = S * (1.f / DIMD);
        float var = Q * (1.f / DIMD) - mu * mu;
        mu_sh = mu;
        rs_sh = rsqrtf(var + LNEPS);
    }
    __syncthreads();
    const float mu = mu_sh, rs = rs_sh;
    const unsigned short* mrow = mod + (size_t)n * MODD;
    const size_t o0 = (size_t)n * DIMD + tid;
    dst[o0]       = f2bf((v0 - mu) * rs * (1.f + bf2f(mrow[scale_off + tid]))       + bf2f(mrow[shift_off + tid]));
    dst[o0 + 256] = f2bf((v1 - mu) * rs * (1.f + bf2f(mrow[scale_off + tid + 256])) + bf2f(mrow[shift_off + tid + 256]));
}

// ---------------------------------------------------------------------------
// MFMA flash attention v2 (bf16, fp32 acc), causal, transposed-score scheme.
// (unchanged from round 4)
// ---------------------------------------------------------------------------
__global__ __launch_bounds__(256, 2) void attn_mfma(
    const unsigned short* __restrict__ qkv, unsigned short* __restrict__ outb)
{
    __shared__ unsigned short Kt[128][72];     // K[kpos][d], +8 pad
    __shared__ unsigned short Vt[64][136];     // V^T: Vt[d][kpos], +8 pad
    __shared__ unsigned short Ps[4][32][136];  // per-wave P[q][kpos]

    const int qi = (TT / 128 - 1) - blockIdx.x;   // long blocks first
    const int h = blockIdx.y, b = blockIdx.z;
    const int tid = threadIdx.x;
    const int w = tid >> 6;
    const int lane = tid & 63;
    const int quad = lane >> 4;
    const int l16 = lane & 15;

    const int qw = qi * 128 + w * 32;
    const size_t tokbase = (size_t)b * TT;

    // Q fragments (B operand of S^T = K·Q^T); fold log2(e)/8 into the bf16
    short8 qf[2][2];
    #pragma unroll
    for (int nt = 0; nt < 2; nt++) {
        const unsigned short* qp = qkv + (tokbase + qw + nt * 16 + l16) * 1536 + h * 64 + quad * 8;
        #pragma unroll
        for (int hd = 0; hd < 2; hd++) {
            short8 raw = *(const short8*)(qp + hd * 32);
            short8 f;
            #pragma unroll
            for (int j = 0; j < 8; j++)
                f[j] = (short)f2bf(bf2f((unsigned short)raw[j]) * LOG2E_8);
            qf[nt][hd] = f;
        }
    }

    f32x4 Oa[4][2];   // [d-tile][q-tile]; col=lane&15=q, row=quad*4+r=d
    float mrun[2] = {-INFINITY, -INFINITY}, lrun[2] = {0.f, 0.f};
    #pragma unroll
    for (int mt = 0; mt < 4; mt++)
        #pragma unroll
        for (int nt = 0; nt < 2; nt++) Oa[mt][nt] = (f32x4){0.f, 0.f, 0.f, 0.f};

    const int nkt = qi + 1;
    const int vk0 = (tid & 63) * 2;        // k-pair this thread transposes
    const int vdb = (tid >> 6) * 8;        // d-chunk base

    short8 kpre[4], vpre[4];
    auto prefetchKV = [&](int kt) {
        const unsigned short* kb = qkv + (tokbase + (size_t)kt * 128) * 1536 + 512 + h * 64;
        #pragma unroll
        for (int it = 0; it < 4; it++) {
            const int i = tid + it * 256;
            kpre[it] = *(const short8*)(kb + (size_t)(i >> 3) * 1536 + (i & 7) * 8);
        }
        const unsigned short* vb = qkv + (tokbase + (size_t)kt * 128 + vk0) * 1536 + 1024 + h * 64;
        #pragma unroll
        for (int p = 0; p < 2; p++) {
            vpre[2 * p]     = *(const short8*)(vb + p * 32 + vdb);
            vpre[2 * p + 1] = *(const short8*)(vb + 1536 + p * 32 + vdb);
        }
    };
    auto storeKV = [&]() {
        #pragma unroll
        for (int it = 0; it < 4; it++) {
            const int i = tid + it * 256;
            *(short8*)&Kt[i >> 3][(i & 7) * 8] = kpre[it];
        }
        #pragma unroll
        for (int p = 0; p < 2; p++)
            #pragma unroll
            for (int j = 0; j < 8; j++) {
                const int d = p * 32 + vdb + j;
                *(unsigned*)&Vt[d][vk0] =
                    (unsigned)(unsigned short)vpre[2 * p][j]
                    | ((unsigned)(unsigned short)vpre[2 * p + 1][j] << 16);
            }
    };

    prefetchKV(0);
    storeKV();
    __syncthreads();

    for (int kt = 0; kt < nkt; kt++) {
        const bool haveNext = (kt + 1 < nkt);
        if (haveNext) prefetchKV(kt + 1);   // loads in flight during compute

        // ---- S^T = K·Q^T ----  A = K (rows = kpos), B = Q^T
        short8 af[8][2];
        #pragma unroll
        for (int mk = 0; mk < 8; mk++) {
            af[mk][0] = *(const short8*)&Kt[mk * 16 + l16][quad * 8];
            af[mk][1] = *(const short8*)&Kt[mk * 16 + l16][32 + quad * 8];
        }
        #pragma unroll
        for (int nt = 0; nt < 2; nt++) {
            f32x4 st[8];
            #pragma unroll
            for (int mk = 0; mk < 8; mk++) {
                st[mk] = (f32x4){0.f, 0.f, 0.f, 0.f};
                st[mk] = mfma_bf16(af[mk][0], qf[nt][0], st[mk]);
                st[mk] = mfma_bf16(af[mk][1], qf[nt][1], st[mk]);
            }
            if (kt == qi) {   // diagonal tile: causal mask
                const int qrel = w * 32 + nt * 16 + l16;
                #pragma unroll
                for (int mk = 0; mk < 8; mk++)
                    #pragma unroll
                    for (int r = 0; r < 4; r++)
                        if (mk * 16 + quad * 4 + r > qrel) st[mk][r] = -INFINITY;
            }
            // per-lane softmax (q = fixed per lane); cross-quad reduce only
            float tm = -INFINITY;
            #pragma unroll
            for (int mk = 0; mk < 8; mk++)
                #pragma unroll
                for (int r = 0; r < 4; r++) tm = fmaxf(tm, st[mk][r]);
            tm = fmaxf(tm, __shfl_xor(tm, 16));
            tm = fmaxf(tm, __shfl_xor(tm, 32));
            const float mn = fmaxf(mrun[nt], tm);
            const float alpha = __builtin_amdgcn_exp2f(mrun[nt] - mn);
            mrun[nt] = mn;
            float ts = 0.f;
            #pragma unroll
            for (int mk = 0; mk < 8; mk++) {
                const float p0 = __builtin_amdgcn_exp2f(st[mk][0] - mn);
                const float p1 = __builtin_amdgcn_exp2f(st[mk][1] - mn);
                const float p2 = __builtin_amdgcn_exp2f(st[mk][2] - mn);
                const float p3 = __builtin_amdgcn_exp2f(st[mk][3] - mn);
                ts += (p0 + p1) + (p2 + p3);
                const unsigned long long pk =
                    (unsigned long long)f2bf(p0)
                    | ((unsigned long long)f2bf(p1) << 16)
                    | ((unsigned long long)f2bf(p2) << 32)
                    | ((unsigned long long)f2bf(p3) << 48);
                *(unsigned long long*)&Ps[w][nt * 16 + l16][mk * 16 + quad * 4] = pk;
            }
            ts += __shfl_xor(ts, 16);
            ts += __shfl_xor(ts, 32);
            lrun[nt] = lrun[nt] * alpha + ts;
            #pragma unroll
            for (int mt = 0; mt < 4; mt++) Oa[mt][nt] *= alpha;
        }
        __threadfence_block();   // own Ps stores -> reads ordering

        // ---- O^T += V^T·P^T ----  A = V^T, B = P^T (read from P[q][k])
        short8 pf0[4], pf1[4];
        #pragma unroll
        for (int kc = 0; kc < 4; kc++) {
            pf0[kc] = *(const short8*)&Ps[w][l16][kc * 32 + quad * 8];
            pf1[kc] = *(const short8*)&Ps[w][16 + l16][kc * 32 + quad * 8];
        }
        #pragma unroll
        for (int mt = 0; mt < 4; mt++)
            #pragma unroll
            for (int kc = 0; kc < 4; kc++) {
                const short8 vf = *(const short8*)&Vt[mt * 16 + l16][kc * 32 + quad * 8];
                Oa[mt][0] = mfma_bf16(vf, pf0[kc], Oa[mt][0]);
                Oa[mt][1] = mfma_bf16(vf, pf1[kc], Oa[mt][1]);
            }

        __syncthreads();            // all LDS reads of tile kt done
        if (haveNext) storeKV();    // implicit vmcnt waits on prefetched regs
        __syncthreads();            // staging visible
    }

    // ---- epilogue: O /= l ----  lane owns q-row (per n-tile)
    #pragma unroll
    for (int nt = 0; nt < 2; nt++) {
        const float inv = 1.f / lrun[nt];
        const size_t tok = tokbase + qw + nt * 16 + l16;
        #pragma unroll
        for (int mt = 0; mt < 4; mt++) {
            const unsigned long long pk =
                (unsigned long long)f2bf(Oa[mt][nt][0] * inv)
                | ((unsigned long long)f2bf(Oa[mt][nt][1] * inv) << 16)
                | ((unsigned long long)f2bf(Oa[mt][nt][2] * inv) << 32)
                | ((unsigned long long)f2bf(Oa[mt][nt][3] * inv) << 48);
            *(unsigned long long*)&outb[tok * DIMD + h * 64 + mt * 16 + quad * 4] = pk;
        }
    }
}

// ---------------------------------------------------------------------------
extern "C" void kernel_launch(void* const* d_in, const int* in_sizes, int n_in,
                              void* d_out, int out_size, void* d_ws, size_t ws_size,
                              hipStream_t stream)
{
    (void)in_sizes; (void)n_in; (void)out_size; (void)ws_size;

    const float* x    = (const float*)d_in[0];
    const float* aemb = (const float*)d_in[1];
    const float* Wqkv = (const float*)d_in[3];
    const float* Wout = (const float*)d_in[4];
    const float* bout = (const float*)d_in[5];
    const float* W1   = (const float*)d_in[6];
    const float* b1   = (const float*)d_in[7];
    const float* W2   = (const float*)d_in[8];
    const float* b2   = (const float*)d_in[9];
    const float* Wmod = (const float*)d_in[10];
    const float* bmod = (const float*)d_in[11];

    float* out = (float*)d_out;

    // workspace layout
    char* p = (char*)d_ws;
    unsigned short* modw = (unsigned short*)p; p += (size_t)NTOK * MODD * 2;   // bf16 mod
    unsigned short* h12  = (unsigned short*)p; p += (size_t)NTOK * DIMD * 2;
    unsigned short* qkvb = (unsigned short*)p; p += (size_t)NTOK * 1536 * 2;
    unsigned short* attw = (unsigned short*)p; p += (size_t)NTOK * DIMD * 2;
    unsigned short* hid  = qkvb;        // reuses qkvb+attw (8192*2048*2 exactly)
    unsigned short* sact = (unsigned short*)p; p += (size_t)NTOK * ADIMD * 2;
    unsigned short* wq = (unsigned short*)p;   p += (size_t)1536 * 512 * 2;
    unsigned short* wo = (unsigned short*)p;   p += (size_t)512 * 512 * 2;
    unsigned short* w1 = (unsigned short*)p;   p += (size_t)2048 * 512 * 2;
    unsigned short* w2 = (unsigned short*)p;   p += (size_t)512 * 2048 * 2;
    unsigned short* wm = (unsigned short*)p;   p += (size_t)3072 * 256 * 2;

    // 0) all dtype conversions in one launch
    CvtArgs ca;
    ca.s[0] = Wqkv; ca.d[0] = wq;
    ca.s[1] = Wout; ca.d[1] = wo;
    ca.s[2] = W1;   ca.d[2] = w1;
    ca.s[3] = W2;   ca.d[3] = w2;
    ca.s[4] = Wmod; ca.d[4] = wm;
    ca.s[5] = aemb; ca.d[5] = sact;   // silu applied
    const int n4s[6] = {1536 * 512 / 4, 512 * 512 / 4, 2048 * 512 / 4,
                        512 * 2048 / 4, 3072 * 256 / 4, NTOK * ADIMD / 4};
    ca.cum[0] = 0;
    for (int i = 0; i < 6; i++) ca.cum[i + 1] = ca.cum[i] + n4s[i];
    cvt_all<<<(ca.cum[6] + 255) / 256, 256, 0, stream>>>(ca);

    // 1) mod = silu(action_emb) @ Wmod^T + bmod  (bf16 out)
    gemm_bf16<5, 128><<<dim3(MODD / 128, NTOK / 128), 256, 0, stream>>>(
        sact, wm, bmod, nullptr, nullptr, NTOK, MODD, ADIMD, modw);

    // 2) h1 = LN(x)*(1+scale1)+shift1  (bf16 out)
    adaln_ln<<<NTOK, 256, 0, stream>>>(x, modw, h12, 0, 512);

    // 3) qkv = h1 @ Wqkv^T  (bf16 out)
    gemm_bf16<0, 128><<<dim3(1536 / 128, NTOK / 128), 256, 0, stream>>>(
        h12, wq, nullptr, nullptr, nullptr, NTOK, 1536, DIMD, qkvb);

    // 4) attention (bf16 flash MFMA v2)
    attn_mfma<<<dim3(TT / 128, HH, BB), 256, 0, stream>>>(qkvb, attw);

    // 5) x_mid = x + gate1 * (attw @ Wout^T + bout)  (fp32 out -> d_out)
    gemm_bf16<3, 64><<<dim3(DIMD / 64, NTOK / 128), 256, 0, stream>>>(
        attw, wo, bout, x, modw, NTOK, DIMD, DIMD, out);

    // 6) h2 = LN(x_mid)*(1+scale2)+shift2  (bf16 out)
    adaln_ln<<<NTOK, 256, 0, stream>>>(out, modw, h12, 1536, 2048);

    // 7) hid = gelu(h2 @ W1^T + b1)  (bf16 out)
    gemm_bf16<2, 128><<<dim3(MLPD / 128, NTOK / 128), 256, 0, stream>>>(
        h12, w1, b1, nullptr, nullptr, NTOK, MLPD, DIMD, hid);

    // 8) d_out = x_mid + gate2 * (hid @ W2^T + b2)  (fp32 RMW)
    gemm_bf16<4, 64><<<dim3(DIMD / 64, NTOK / 128), 256, 0, stream>>>(
        hid, w2, b2, nullptr, modw, NTOK, DIMD, MLPD, out);
}

// Round 6
// 337.789 us; speedup vs baseline: 5.5010x; 1.0009x over previous
//
#include <hip/hip_runtime.h>
#include <math.h>
#include <stdint.h>

// Problem constants
#define BB 4
#define TT 2048
#define NTOK 8192        // B*T
#define DIMD 512
#define HH 8
#define DHH 64
#define MLPD 2048
#define ADIMD 256
#define MODD 3072        // 6*DIM
#define LNEPS 1e-5f
#define LOG2E_8 0.18033688011112042f   // log2(e)/8

typedef short short8 __attribute__((ext_vector_type(8)));
typedef unsigned short ushort4v __attribute__((ext_vector_type(4)));
typedef __bf16 bf16x8 __attribute__((ext_vector_type(8)));
typedef float f32x4 __attribute__((ext_vector_type(4)));

static __device__ __forceinline__ unsigned short f2bf(float f) {
    union { float f; unsigned u; } v; v.f = f;
    unsigned r = v.u + 0x7fffu + ((v.u >> 16) & 1u);
    return (unsigned short)(r >> 16);
}
static __device__ __forceinline__ float bf2f(unsigned short u) {
    union { unsigned u; float f; } v; v.u = (unsigned)u << 16; return v.f;
}

static __device__ __forceinline__ f32x4 mfma_bf16(short8 a, short8 b, f32x4 c) {
    return __builtin_amdgcn_mfma_f32_16x16x32_bf16(
        __builtin_bit_cast(bf16x8, a), __builtin_bit_cast(bf16x8, b), c, 0, 0, 0);
}

// ---------------------------------------------------------------------------
// Merged fp32->bf16 conversion: 5 weights + silu(action_emb), one launch
// ---------------------------------------------------------------------------
struct CvtArgs {
    const float* s[6];
    unsigned short* d[6];
    int cum[7];   // cumulative n4 offsets
};
__global__ __launch_bounds__(256) void cvt_all(CvtArgs a)
{
    const int i = blockIdx.x * 256 + threadIdx.x;
    if (i >= a.cum[6]) return;
    int seg = 0;
    #pragma unroll
    for (int k = 1; k < 6; k++) seg += (i >= a.cum[k]);
    const int off = i - a.cum[seg];
    float4 v = ((const float4*)a.s[seg])[off];
    if (seg == 5) {   // silu for action_emb
        v.x = v.x / (1.f + __expf(-v.x));
        v.y = v.y / (1.f + __expf(-v.y));
        v.z = v.z / (1.f + __expf(-v.z));
        v.w = v.w / (1.f + __expf(-v.w));
    }
    ushort4v o = { f2bf(v.x), f2bf(v.y), f2bf(v.z), f2bf(v.w) };
    ((ushort4v*)a.d[seg])[off] = o;
}

// ---------------------------------------------------------------------------
// bf16 MFMA NT GEMM, pipelined K-loop (unchanged from round 5)
// EPI: 0 = bf16 store
//      2 = bf16 store gelu_exact(acc + bias[n])
//      3 = fp32 store res[m,n] + mod[m*3072+1024+n]*(acc+bias[n])
//      4 = fp32 RMW    C[m,n] + mod[m*3072+2560+n]*(acc+bias[n])
//      5 = bf16 store acc + bias[n]
// ---------------------------------------------------------------------------
template<int EPI, int BN>
__global__ __launch_bounds__(256) void gemm_bf16(
    const unsigned short* __restrict__ A, const unsigned short* __restrict__ Bw,
    const float* __restrict__ bias, const float* __restrict__ res,
    const unsigned short* __restrict__ mod,
    int M, int N, int K,
    void* __restrict__ Cv)
{
    constexpr int MT = (BN == 128) ? 4 : 2;   // per-wave m-tiles (of 16)
    constexpr int NPB = (BN == 128) ? 4 : 2;  // B staging passes per thread
    __shared__ unsigned short As[128 * 72];   // [row][k], stride 72 (bank-balanced)
    __shared__ unsigned short Bs[BN * 72];

    const int tid = threadIdx.x;
    const int w = tid >> 6, lane = tid & 63;
    const int quad = lane >> 4, l16 = lane & 15;
    const int wrow = (BN == 128) ? (w >> 1) * 64 : w * 32;
    const int wcol = (BN == 128) ? (w & 1) * 64 : 0;
    const int row0 = blockIdx.y * 128, col0 = blockIdx.x * BN;

    const int srow = tid >> 3;          // 0..31
    const int skc  = (tid & 7) * 8;     // 0..56

    f32x4 acc[MT][4];
    #pragma unroll
    for (int i = 0; i < MT; i++)
        #pragma unroll
        for (int j = 0; j < 4; j++) acc[i][j] = (f32x4){0.f, 0.f, 0.f, 0.f};

    short8 pA[4], pB[NPB];
    auto prefetch = [&](int k0) {
        #pragma unroll
        for (int p = 0; p < 4; p++)
            pA[p] = *(const short8*)&A[(size_t)(row0 + srow + p * 32) * K + k0 + skc];
        #pragma unroll
        for (int p = 0; p < NPB; p++)
            pB[p] = *(const short8*)&Bw[(size_t)(col0 + srow + p * 32) * K + k0 + skc];
    };
    auto stage = [&]() {
        #pragma unroll
        for (int p = 0; p < 4; p++)
            *(short8*)&As[(srow + p * 32) * 72 + skc] = pA[p];
        #pragma unroll
        for (int p = 0; p < NPB; p++)
            *(short8*)&Bs[(srow + p * 32) * 72 + skc] = pB[p];
    };

    prefetch(0);
    stage();
    __syncthreads();

    for (int k0 = 0; k0 < K; k0 += 64) {
        const bool more = (k0 + 64 < K);
        if (more) prefetch(k0 + 64);    // loads in flight during MFMAs

        #pragma unroll
        for (int ks = 0; ks < 2; ks++) {
            short8 af[MT], bf[4];
            #pragma unroll
            for (int mt = 0; mt < MT; mt++)
                af[mt] = *(const short8*)&As[(wrow + mt * 16 + l16) * 72 + ks * 32 + quad * 8];
            #pragma unroll
            for (int nt = 0; nt < 4; nt++)
                bf[nt] = *(const short8*)&Bs[(wcol + nt * 16 + l16) * 72 + ks * 32 + quad * 8];
            #pragma unroll
            for (int nt = 0; nt < 4; nt++)
                #pragma unroll
                for (int mt = 0; mt < MT; mt++)
                    acc[mt][nt] = mfma_bf16(af[mt], bf[nt], acc[mt][nt]);
        }
        __syncthreads();                // all LDS reads of this tile done
        if (more) stage();              // vmcnt wait lands here, after compute
        __syncthreads();                // staging visible
    }

    float* Cf = (float*)Cv;
    unsigned short* Cb = (unsigned short*)Cv;
    #pragma unroll
    for (int mt = 0; mt < MT; mt++) {
        #pragma unroll
        for (int r = 0; r < 4; r++) {
            const int row = row0 + wrow + mt * 16 + quad * 4 + r;
            #pragma unroll
            for (int nt = 0; nt < 4; nt++) {
                const int col = col0 + wcol + nt * 16 + l16;
                const size_t idx = (size_t)row * N + col;
                const float v = acc[mt][nt][r];
                if (EPI == 0) {
                    Cb[idx] = f2bf(v);
                } else if (EPI == 2) {
                    float t = v + bias[col];
                    Cb[idx] = f2bf(0.5f * t * (1.f + erff(t * 0.70710678118654752f)));
                } else if (EPI == 3) {
                    float t = v + bias[col];
                    Cf[idx] = res[idx] + bf2f(mod[(size_t)row * MODD + 1024 + col]) * t;
                } else if (EPI == 4) {
                    float t = v + bias[col];
                    Cf[idx] = Cf[idx] + bf2f(mod[(size_t)row * MODD + 2560 + col]) * t;
                } else if (EPI == 5) {
                    Cb[idx] = f2bf(v + bias[col]);
                }
            }
        }
    }
}

// ---------------------------------------------------------------------------
// adaLN: dst(bf16)[n,:] = LN(src[n,:])*(1+mod[n,scale:+512]) + mod[n,shift:+512]
// ---------------------------------------------------------------------------
__global__ __launch_bounds__(256) void adaln_ln(
    const float* __restrict__ src, const unsigned short* __restrict__ mod,
    unsigned short* __restrict__ dst, int shift_off, int scale_off)
{
    const int n = blockIdx.x;
    const int tid = threadIdx.x;
    const float* xr = src + (size_t)n * DIMD;
    float v0 = xr[tid], v1 = xr[tid + 256];
    float s = v0 + v1;
    float q = v0 * v0 + v1 * v1;
    #pragma unroll
    for (int o = 32; o > 0; o >>= 1) {
        s += __shfl_down(s, o);
        q += __shfl_down(q, o);
    }
    __shared__ float sh[8];
    __shared__ float mu_sh, rs_sh;
    const int wid = tid >> 6, lane = tid & 63;
    if (lane == 0) { sh[wid] = s; sh[wid + 4] = q; }
    __syncthreads();
    if (tid == 0) {
        float S = sh[0] + sh[1] + sh[2] + sh[3];
        float Q = sh[4] + sh[5] + sh[6] + sh[7];
        float mu = S * (1.f / DIMD);
        float var = Q * (1.f / DIMD) - mu * mu;
        mu_sh = mu;
        rs_sh = rsqrtf(var + LNEPS);
    }
    __syncthreads();
    const float mu = mu_sh, rs = rs_sh;
    const unsigned short* mrow = mod + (size_t)n * MODD;
    const size_t o0 = (size_t)n * DIMD + tid;
    dst[o0]       = f2bf((v0 - mu) * rs * (1.f + bf2f(mrow[scale_off + tid]))       + bf2f(mrow[shift_off + tid]));
    dst[o0 + 256] = f2bf((v1 - mu) * rs * (1.f + bf2f(mrow[scale_off + tid + 256])) + bf2f(mrow[shift_off + tid + 256]));
}

// ---------------------------------------------------------------------------
// MFMA flash attention v3 (bf16, fp32 acc), causal, transposed-score scheme.
// qkv: [NTOK,1536] bf16 (q/k/v at +0/+512/+1024, inner h*64+d). out bf16 [NTOK,512].
// Grid (T/64=32, H, B) = 1024 blocks; 4 waves; wave = 16 q rows. K-tile = 64.
// LDS 27.6 KB -> ~4 blocks/CU (VGPR-capped), 2x round-5 occupancy.
// S^T = K·Q^T: C col=lane&15 = q-row -> per-lane softmax, cross-quad shfl only.
// ---------------------------------------------------------------------------
__global__ __launch_bounds__(256, 4) void attn_mfma(
    const unsigned short* __restrict__ qkv, unsigned short* __restrict__ outb)
{
    __shared__ unsigned short Kt[64][72];     // K[kpos][d], +8 pad
    __shared__ unsigned short Vt[64][72];     // V^T: Vt[d][kpos], +8 pad
    __shared__ unsigned short Ps[4][16][72];  // per-wave P[q][kpos]

    const int qi = (TT / 64 - 1) - blockIdx.x;    // long blocks first
    const int h = blockIdx.y, b = blockIdx.z;
    const int tid = threadIdx.x;
    const int w = tid >> 6;
    const int lane = tid & 63;
    const int quad = lane >> 4;
    const int l16 = lane & 15;

    const int qw = qi * 64 + w * 16;
    const size_t tokbase = (size_t)b * TT;

    // Q fragment (B operand of S^T = K·Q^T); fold log2(e)/8 into the bf16
    short8 qf[2];
    {
        const unsigned short* qp = qkv + (tokbase + qw + l16) * 1536 + h * 64 + quad * 8;
        #pragma unroll
        for (int hd = 0; hd < 2; hd++) {
            short8 raw = *(const short8*)(qp + hd * 32);
            short8 f;
            #pragma unroll
            for (int j = 0; j < 8; j++)
                f[j] = (short)f2bf(bf2f((unsigned short)raw[j]) * LOG2E_8);
            qf[hd] = f;
        }
    }

    f32x4 Oa[4];   // [d-tile]; col=lane&15=q, row=quad*4+r=d
    float mrun = -INFINITY, lrun = 0.f;
    #pragma unroll
    for (int mt = 0; mt < 4; mt++) Oa[mt] = (f32x4){0.f, 0.f, 0.f, 0.f};

    const int nkt = qi + 1;
    const int vk0 = (tid & 31) * 2;        // k-pair this thread transposes
    const int vdb = (tid >> 5) * 8;        // d-chunk base (8 groups x 8 d)

    short8 kpre[2], vpre[2];
    auto prefetchKV = [&](int kt) {
        const unsigned short* kb = qkv + (tokbase + (size_t)kt * 64) * 1536 + 512 + h * 64;
        #pragma unroll
        for (int it = 0; it < 2; it++) {
            const int i = tid + it * 256;
            kpre[it] = *(const short8*)(kb + (size_t)(i >> 3) * 1536 + (i & 7) * 8);
        }
        const unsigned short* vb = qkv + (tokbase + (size_t)kt * 64 + vk0) * 1536 + 1024 + h * 64 + vdb;
        vpre[0] = *(const short8*)vb;
        vpre[1] = *(const short8*)(vb + 1536);
    };
    auto storeKV = [&]() {
        #pragma unroll
        for (int it = 0; it < 2; it++) {
            const int i = tid + it * 256;
            *(short8*)&Kt[i >> 3][(i & 7) * 8] = kpre[it];
        }
        #pragma unroll
        for (int j = 0; j < 8; j++) {
            *(unsigned*)&Vt[vdb + j][vk0] =
                (unsigned)(unsigned short)vpre[0][j]
                | ((unsigned)(unsigned short)vpre[1][j] << 16);
        }
    };

    prefetchKV(0);
    storeKV();
    __syncthreads();

    for (int kt = 0; kt < nkt; kt++) {
        const bool haveNext = (kt + 1 < nkt);
        if (haveNext) prefetchKV(kt + 1);   // loads in flight during compute

        // ---- S^T = K·Q^T ----  A = K (rows = kpos), B = Q^T
        f32x4 st[4];
        #pragma unroll
        for (int mk = 0; mk < 4; mk++) {
            const short8 a0 = *(const short8*)&Kt[mk * 16 + l16][quad * 8];
            const short8 a1 = *(const short8*)&Kt[mk * 16 + l16][32 + quad * 8];
            st[mk] = (f32x4){0.f, 0.f, 0.f, 0.f};
            st[mk] = mfma_bf16(a0, qf[0], st[mk]);
            st[mk] = mfma_bf16(a1, qf[1], st[mk]);
        }
        if (kt == qi) {   // diagonal tile: causal mask (k > q -> -inf)
            const int qpos = qw + l16;
            #pragma unroll
            for (int mk = 0; mk < 4; mk++)
                #pragma unroll
                for (int r = 0; r < 4; r++)
                    if (kt * 64 + mk * 16 + quad * 4 + r > qpos) st[mk][r] = -INFINITY;
        }
        // ---- per-lane softmax (q fixed per lane); cross-quad reduce only ----
        float tm = -INFINITY;
        #pragma unroll
        for (int mk = 0; mk < 4; mk++)
            #pragma unroll
            for (int r = 0; r < 4; r++) tm = fmaxf(tm, st[mk][r]);
        tm = fmaxf(tm, __shfl_xor(tm, 16));
        tm = fmaxf(tm, __shfl_xor(tm, 32));
        const float mn = fmaxf(mrun, tm);
        const float alpha = __builtin_amdgcn_exp2f(mrun - mn);
        mrun = mn;
        float ts = 0.f;
        #pragma unroll
        for (int mk = 0; mk < 4; mk++) {
            const float p0 = __builtin_amdgcn_exp2f(st[mk][0] - mn);
            const float p1 = __builtin_amdgcn_exp2f(st[mk][1] - mn);
            const float p2 = __builtin_amdgcn_exp2f(st[mk][2] - mn);
            const float p3 = __builtin_amdgcn_exp2f(st[mk][3] - mn);
            ts += (p0 + p1) + (p2 + p3);
            const unsigned long long pk =
                (unsigned long long)f2bf(p0)
                | ((unsigned long long)f2bf(p1) << 16)
                | ((unsigned long long)f2bf(p2) << 32)
                | ((unsigned long long)f2bf(p3) << 48);
            *(unsigned long long*)&Ps[w][l16][mk * 16 + quad * 4] = pk;
        }
        ts += __shfl_xor(ts, 16);
        ts += __shfl_xor(ts, 32);
        lrun = lrun * alpha + ts;
        #pragma unroll
        for (int mt = 0; mt < 4; mt++) Oa[mt] *= alpha;
        __threadfence_block();   // own Ps stores -> reads ordering

        // ---- O^T += V^T·P^T ----  A = V^T, B = P^T (read from P[q][k])
        short8 pf[2];
        #pragma unroll
        for (int kc = 0; kc < 2; kc++)
            pf[kc] = *(const short8*)&Ps[w][l16][kc * 32 + quad * 8];
        #pragma unroll
        for (int mt = 0; mt < 4; mt++)
            #pragma unroll
            for (int kc = 0; kc < 2; kc++) {
                const short8 vf = *(const short8*)&Vt[mt * 16 + l16][kc * 32 + quad * 8];
                Oa[mt] = mfma_bf16(vf, pf[kc], Oa[mt]);
            }

        __syncthreads();            // all LDS reads of tile kt done
        if (haveNext) storeKV();    // implicit vmcnt waits on prefetched regs
        __syncthreads();            // staging visible
    }

    // ---- epilogue: O /= l ----  lane owns q-row
    {
        const float inv = 1.f / lrun;
        const size_t tok = tokbase + qw + l16;
        #pragma unroll
        for (int mt = 0; mt < 4; mt++) {
            const unsigned long long pk =
                (unsigned long long)f2bf(Oa[mt][0] * inv)
                | ((unsigned long long)f2bf(Oa[mt][1] * inv) << 16)
                | ((unsigned long long)f2bf(Oa[mt][2] * inv) << 32)
                | ((unsigned long long)f2bf(Oa[mt][3] * inv) << 48);
            *(unsigned long long*)&outb[tok * DIMD + h * 64 + mt * 16 + quad * 4] = pk;
        }
    }
}

// ---------------------------------------------------------------------------
extern "C" void kernel_launch(void* const* d_in, const int* in_sizes, int n_in,
                              void* d_out, int out_size, void* d_ws, size_t ws_size,
                              hipStream_t stream)
{
    (void)in_sizes; (void)n_in; (void)out_size; (void)ws_size;

    const float* x    = (const float*)d_in[0];
    const float* aemb = (const float*)d_in[1];
    const float* Wqkv = (const float*)d_in[3];
    const float* Wout = (const float*)d_in[4];
    const float* bout = (const float*)d_in[5];
    const float* W1   = (const float*)d_in[6];
    const float* b1   = (const float*)d_in[7];
    const float* W2   = (const float*)d_in[8];
    const float* b2   = (const float*)d_in[9];
    const float* Wmod = (const float*)d_in[10];
    const float* bmod = (const float*)d_in[11];

    float* out = (float*)d_out;

    // workspace layout
    char* p = (char*)d_ws;
    unsigned short* modw = (unsigned short*)p; p += (size_t)NTOK * MODD * 2;   // bf16 mod
    unsigned short* h12  = (unsigned short*)p; p += (size_t)NTOK * DIMD * 2;
    unsigned short* qkvb = (unsigned short*)p; p += (size_t)NTOK * 1536 * 2;
    unsigned short* attw = (unsigned short*)p; p += (size_t)NTOK * DIMD * 2;
    unsigned short* hid  = qkvb;        // reuses qkvb+attw (8192*2048*2 exactly)
    unsigned short* sact = (unsigned short*)p; p += (size_t)NTOK * ADIMD * 2;
    unsigned short* wq = (unsigned short*)p;   p += (size_t)1536 * 512 * 2;
    unsigned short* wo = (unsigned short*)p;   p += (size_t)512 * 512 * 2;
    unsigned short* w1 = (unsigned short*)p;   p += (size_t)2048 * 512 * 2;
    unsigned short* w2 = (unsigned short*)p;   p += (size_t)512 * 2048 * 2;
    unsigned short* wm = (unsigned short*)p;   p += (size_t)3072 * 256 * 2;

    // 0) all dtype conversions in one launch
    CvtArgs ca;
    ca.s[0] = Wqkv; ca.d[0] = wq;
    ca.s[1] = Wout; ca.d[1] = wo;
    ca.s[2] = W1;   ca.d[2] = w1;
    ca.s[3] = W2;   ca.d[3] = w2;
    ca.s[4] = Wmod; ca.d[4] = wm;
    ca.s[5] = aemb; ca.d[5] = sact;   // silu applied
    const int n4s[6] = {1536 * 512 / 4, 512 * 512 / 4, 2048 * 512 / 4,
                        512 * 2048 / 4, 3072 * 256 / 4, NTOK * ADIMD / 4};
    ca.cum[0] = 0;
    for (int i = 0; i < 6; i++) ca.cum[i + 1] = ca.cum[i] + n4s[i];
    cvt_all<<<(ca.cum[6] + 255) / 256, 256, 0, stream>>>(ca);

    // 1) mod = silu(action_emb) @ Wmod^T + bmod  (bf16 out)
    gemm_bf16<5, 128><<<dim3(MODD / 128, NTOK / 128), 256, 0, stream>>>(
        sact, wm, bmod, nullptr, nullptr, NTOK, MODD, ADIMD, modw);

    // 2) h1 = LN(x)*(1+scale1)+shift1  (bf16 out)
    adaln_ln<<<NTOK, 256, 0, stream>>>(x, modw, h12, 0, 512);

    // 3) qkv = h1 @ Wqkv^T  (bf16 out)
    gemm_bf16<0, 128><<<dim3(1536 / 128, NTOK / 128), 256, 0, stream>>>(
        h12, wq, nullptr, nullptr, nullptr, NTOK, 1536, DIMD, qkvb);

    // 4) attention (bf16 flash MFMA v3)
    attn_mfma<<<dim3(TT / 64, HH, BB), 256, 0, stream>>>(qkvb, attw);

    // 5) x_mid = x + gate1 * (attw @ Wout^T + bout)  (fp32 out -> d_out)
    gemm_bf16<3, 64><<<dim3(DIMD / 64, NTOK / 128), 256, 0, stream>>>(
        attw, wo, bout, x, modw, NTOK, DIMD, DIMD, out);

    // 6) h2 = LN(x_mid)*(1+scale2)+shift2  (bf16 out)
    adaln_ln<<<NTOK, 256, 0, stream>>>(out, modw, h12, 1536, 2048);

    // 7) hid = gelu(h2 @ W1^T + b1)  (bf16 out)
    gemm_bf16<2, 128><<<dim3(MLPD / 128, NTOK / 128), 256, 0, stream>>>(
        h12, w1, b1, nullptr, nullptr, NTOK, MLPD, DIMD, hid);

    // 8) d_out = x_mid + gate2 * (hid @ W2^T + b2)  (fp32 RMW)
    gemm_bf16<4, 64><<<dim3(DIMD / 64, NTOK / 128), 256, 0, stream>>>(
        hid, w2, b2, nullptr, modw, NTOK, DIMD, MLPD, out);
}